// Round 1
// baseline (995.369 us; speedup 1.0000x reference)
//
#include <hip/hip_runtime.h>
#include <math.h>

#define S_LEN 2048
#define E_DIM 1024
#define NHEAD 8
#define DHEAD 128

constexpr float RSQ_DH  = 0.08838834764831843f; // 1/sqrt(128)
constexpr float EPS_NORM = 1e-6f;
constexpr float LN_EPS_C = 1e-6f;

__device__ inline float dot4f(float4 a, float4 b) {
  return a.x*b.x + a.y*b.y + a.z*b.z + a.w*b.w;
}

// ---------------- Kernel 1: gate preactivations ----------------
__global__ __launch_bounds__(256) void gates_kernel(
    const float* __restrict__ q, const float* __restrict__ k, const float* __restrict__ v,
    const float* __restrict__ Wi, const float* __restrict__ bi,
    const float* __restrict__ Wf, const float* __restrict__ bf,
    float* __restrict__ ig_pre, float* __restrict__ fg_pre) {
  const int t = threadIdx.x;
  const int row0 = blockIdx.x * 4;
  float p[4][16];
#pragma unroll
  for (int rr = 0; rr < 4; ++rr)
#pragma unroll
    for (int c = 0; c < 16; ++c) p[rr][c] = 0.f;

  for (int i = 0; i < 12; ++i) {
    const int e = t + 256 * i;
    const float4 a0 = *(const float4*)(Wi + (size_t)e*8);
    const float4 a1 = *(const float4*)(Wi + (size_t)e*8 + 4);
    const float4 b0 = *(const float4*)(Wf + (size_t)e*8);
    const float4 b1 = *(const float4*)(Wf + (size_t)e*8 + 4);
    float wv[16] = {a0.x,a0.y,a0.z,a0.w, a1.x,a1.y,a1.z,a1.w,
                    b0.x,b0.y,b0.z,b0.w, b1.x,b1.y,b1.z,b1.w};
    const float* base; int eo;
    if (e < E_DIM)        { base = q; eo = e; }
    else if (e < 2*E_DIM) { base = k; eo = e - E_DIM; }
    else                  { base = v; eo = e - 2*E_DIM; }
#pragma unroll
    for (int rr = 0; rr < 4; ++rr) {
      const float x = base[(size_t)(row0+rr)*E_DIM + eo];
#pragma unroll
      for (int c = 0; c < 16; ++c) p[rr][c] += x * wv[c];
    }
  }
#pragma unroll
  for (int rr = 0; rr < 4; ++rr)
#pragma unroll
    for (int c = 0; c < 16; ++c) {
      float val = p[rr][c];
      val += __shfl_xor(val, 1);
      val += __shfl_xor(val, 2);
      val += __shfl_xor(val, 4);
      val += __shfl_xor(val, 8);
      val += __shfl_xor(val, 16);
      val += __shfl_xor(val, 32);
      p[rr][c] = val;
    }
  __shared__ float sred[4][4][16];
  const int wid = t >> 6, lane = t & 63;
  if (lane == 0) {
#pragma unroll
    for (int rr = 0; rr < 4; ++rr)
#pragma unroll
      for (int c = 0; c < 16; ++c) sred[wid][rr][c] = p[rr][c];
  }
  __syncthreads();
  if (t < 64) {
    const int rr = t >> 4, c = t & 15;
    float sum = sred[0][rr][c] + sred[1][rr][c] + sred[2][rr][c] + sred[3][rr][c];
    const int h = c & 7;
    const int row = row0 + rr;
    const int b = row / S_LEN, s = row % S_LEN;
    if (c < 8) ig_pre[((size_t)b*NHEAD + h)*S_LEN + s] = sum + bi[h];
    else       fg_pre[((size_t)b*NHEAD + h)*S_LEN + s] = sum + bf[h];
  }
}

// ---------------- Kernel 2: log-sigmoid + cumsum + prefix-max ----------------
__global__ __launch_bounds__(256) void scan_kernel(
    const float* __restrict__ ig_pre, const float* __restrict__ fg_pre,
    float* __restrict__ cs_out, float* __restrict__ g_out, float* __restrict__ gmax_out) {
  const int bhh = blockIdx.x;
  const int t = threadIdx.x;
  const size_t base = (size_t)bhh * S_LEN;
  float vals[8];
  float run = 0.f;
#pragma unroll
  for (int i = 0; i < 8; ++i) {
    const float x = fg_pre[base + t*8 + i];
    const float lf = fminf(x, 0.f) - log1pf(__expf(-fabsf(x)));
    run += lf;
    vals[i] = run;
  }
  __shared__ float sums[256];
  sums[t] = run;
  __syncthreads();
  for (int off = 1; off < 256; off <<= 1) {
    const float other = (t >= off) ? sums[t - off] : 0.f;
    __syncthreads();
    sums[t] += other;
    __syncthreads();
  }
  const float prefix = (t > 0) ? sums[t-1] : 0.f;
  float g_loc[8], gm_loc[8];
  float lmax = -3.4e38f;
#pragma unroll
  for (int i = 0; i < 8; ++i) {
    const float csv = vals[i] + prefix;
    vals[i] = csv;
    const float gg = ig_pre[base + t*8 + i] - csv;
    g_loc[i] = gg;
    lmax = fmaxf(lmax, gg);
    gm_loc[i] = lmax;
  }
  __shared__ float maxs[256];
  maxs[t] = lmax;
  __syncthreads();
  for (int off = 1; off < 256; off <<= 1) {
    const float other = (t >= off) ? maxs[t - off] : -3.4e38f;
    __syncthreads();
    maxs[t] = fmaxf(maxs[t], other);
    __syncthreads();
  }
  const float pmax = (t > 0) ? maxs[t-1] : -3.4e38f;
#pragma unroll
  for (int i = 0; i < 8; ++i) {
    cs_out[base + t*8 + i]   = vals[i];
    g_out[base + t*8 + i]    = g_loc[i];
    gmax_out[base + t*8 + i] = fmaxf(gm_loc[i], pmax);
  }
}

__device__ inline void ln_write_row(
    float4 a0, float4 a1, float4 a2, float4 a3,
    float den, float cs_i, float gm_i,
    const float* __restrict__ wgt_hd, float* __restrict__ out_row, int base_d) {
  const float norm = fmaxf(fabsf(den), __expf(-(cs_i + gm_i)));
  const float inv = 1.f / (norm + EPS_NORM);
  float hv[16];
  hv[0]=a0.x*inv;  hv[1]=a0.y*inv;  hv[2]=a0.z*inv;  hv[3]=a0.w*inv;
  hv[4]=a1.x*inv;  hv[5]=a1.y*inv;  hv[6]=a1.z*inv;  hv[7]=a1.w*inv;
  hv[8]=a2.x*inv;  hv[9]=a2.y*inv;  hv[10]=a2.z*inv; hv[11]=a2.w*inv;
  hv[12]=a3.x*inv; hv[13]=a3.y*inv; hv[14]=a3.z*inv; hv[15]=a3.w*inv;
  float sum = 0.f, sq = 0.f;
#pragma unroll
  for (int i = 0; i < 16; ++i) { sum += hv[i]; sq += hv[i]*hv[i]; }
  sum += __shfl_xor(sum,1); sum += __shfl_xor(sum,2); sum += __shfl_xor(sum,4);
  sq  += __shfl_xor(sq,1);  sq  += __shfl_xor(sq,2);  sq  += __shfl_xor(sq,4);
  const float mu  = sum * (1.f/128.f);
  const float var = sq  * (1.f/128.f) - mu*mu;
  const float rstd = rsqrtf(var + LN_EPS_C);
#pragma unroll
  for (int c4 = 0; c4 < 4; ++c4) {
    const float4 wv = *(const float4*)(wgt_hd + base_d + c4*32);
    float4 o;
    o.x = (hv[c4*4+0]-mu)*rstd*wv.x;
    o.y = (hv[c4*4+1]-mu)*rstd*wv.y;
    o.z = (hv[c4*4+2]-mu)*rstd*wv.z;
    o.w = (hv[c4*4+3]-mu)*rstd*wv.w;
    *(float4*)(out_row + base_d + c4*32) = o;
  }
}

__global__ __launch_bounds__(256) void mlstm_main(
    const float* __restrict__ q, const float* __restrict__ k, const float* __restrict__ v,
    const float* __restrict__ cs, const float* __restrict__ garr, const float* __restrict__ gmax,
    const float* __restrict__ wgt, float* __restrict__ out) {
  __shared__ float k_lds[32][128];
  __shared__ float v_lds[32][128];
  __shared__ float g_sh[32];
  const int bh = blockIdx.x & 15;
  const int qt = 31 - (blockIdx.x >> 4);
  const int b = bh >> 3, hd = bh & 7;
  const int t = threadIdx.x;
  const int w = t >> 6;
  const int lane = t & 63;
  const int r2 = lane >> 3, dg = lane & 7;
  const int base_d = dg * 4;
  const int ra = qt*64 + w*16 + r2;
  const int rb = ra + 8;
  const size_t bhS = (size_t)bh * S_LEN;
  const float cs_a = cs[bhS + ra], gm_a = gmax[bhS + ra];
  const float cs_b = cs[bhS + rb], gm_b = gmax[bhS + rb];
  const size_t rowa_off = ((size_t)b*S_LEN + ra)*E_DIM + hd*DHEAD;
  const size_t rowb_off = ((size_t)b*S_LEN + rb)*E_DIM + hd*DHEAD;
  const float4 qa0 = *(const float4*)(q + rowa_off + base_d);
  const float4 qa1 = *(const float4*)(q + rowa_off + base_d + 32);
  const float4 qa2 = *(const float4*)(q + rowa_off + base_d + 64);
  const float4 qa3 = *(const float4*)(q + rowa_off + base_d + 96);
  const float4 qb0 = *(const float4*)(q + rowb_off + base_d);
  const float4 qb1 = *(const float4*)(q + rowb_off + base_d + 32);
  const float4 qb2 = *(const float4*)(q + rowb_off + base_d + 64);
  const float4 qb3 = *(const float4*)(q + rowb_off + base_d + 96);
  float4 aa0 = {0,0,0,0}, aa1 = {0,0,0,0}, aa2 = {0,0,0,0}, aa3 = {0,0,0,0};
  float4 ab0 = {0,0,0,0}, ab1 = {0,0,0,0}, ab2 = {0,0,0,0}, ab3 = {0,0,0,0};
  float dena = 0.f, denb = 0.f;
  const int ntiles = 2*qt + 2;
  for (int jt = 0; jt < ntiles; ++jt) {
    const int j0 = jt * 32;
#pragma unroll
    for (int u = 0; u < 4; ++u) {
      const int f = t + 256*u;
      const int jr = f >> 5, cf = f & 31;
      const size_t src = ((size_t)b*S_LEN + (j0 + jr))*E_DIM + hd*DHEAD + cf*4;
      *(float4*)&k_lds[jr][cf*4] = *(const float4*)(k + src);
      *(float4*)&v_lds[jr][cf*4] = *(const float4*)(v + src);
    }
    if (t < 32) g_sh[t] = garr[bhS + j0 + t];
    __syncthreads();
    for (int jj = 0; jj < 32; ++jj) {
      const int jg = j0 + jj;
      const float4 kf0 = *(const float4*)&k_lds[jj][base_d];
      const float4 kf1 = *(const float4*)&k_lds[jj][base_d + 32];
      const float4 kf2 = *(const float4*)&k_lds[jj][base_d + 64];
      const float4 kf3 = *(const float4*)&k_lds[jj][base_d + 96];
      float sa_ = dot4f(qa0,kf0) + dot4f(qa1,kf1) + dot4f(qa2,kf2) + dot4f(qa3,kf3);
      float sb_ = dot4f(qb0,kf0) + dot4f(qb1,kf1) + dot4f(qb2,kf2) + dot4f(qb3,kf3);
      sa_ += __shfl_xor(sa_,1); sa_ += __shfl_xor(sa_,2); sa_ += __shfl_xor(sa_,4);
      sb_ += __shfl_xor(sb_,1); sb_ += __shfl_xor(sb_,2); sb_ += __shfl_xor(sb_,4);
      const float ej = g_sh[jj];
      float wa = sa_ * RSQ_DH * __expf(ej - gm_a);
      float wb = sb_ * RSQ_DH * __expf(ej - gm_b);
      wa = (jg <= ra) ? wa : 0.f;
      wb = (jg <= rb) ? wb : 0.f;
      dena += wa; denb += wb;
      const float4 vf0 = *(const float4*)&v_lds[jj][base_d];
      const float4 vf1 = *(const float4*)&v_lds[jj][base_d + 32];
      const float4 vf2 = *(const float4*)&v_lds[jj][base_d + 64];
      const float4 vf3 = *(const float4*)&v_lds[jj][base_d + 96];
      aa0.x += wa*vf0.x; aa0.y += wa*vf0.y; aa0.z += wa*vf0.z; aa0.w += wa*vf0.w;
      aa1.x += wa*vf1.x; aa1.y += wa*vf1.y; aa1.z += wa*vf1.z; aa1.w += wa*vf1.w;
      aa2.x += wa*vf2.x; aa2.y += wa*vf2.y; aa2.z += wa*vf2.z; aa2.w += wa*vf2.w;
      aa3.x += wa*vf3.x; aa3.y += wa*vf3.y; aa3.z += wa*vf3.z; aa3.w += wa*vf3.w;
      ab0.x += wb*vf0.x; ab0.y += wb*vf0.y; ab0.z += wb*vf0.z; ab0.w += wb*vf0.w;
      ab1.x += wb*vf1.x; ab1.y += wb*vf1.y; ab1.z += wb*vf1.z; ab1.w += wb*vf1.w;
      ab2.x += wb*vf2.x; ab2.y += wb*vf2.y; ab2.z += wb*vf2.z; ab2.w += wb*vf2.w;
      ab3.x += wb*vf3.x; ab3.y += wb*vf3.y; ab3.z += wb*vf3.z; ab3.w += wb*vf3.w;
    }
    __syncthreads();
  }
  ln_write_row(aa0,aa1,aa2,aa3, dena, cs_a, gm_a, wgt + hd*DHEAD, out + rowa_off, base_d);
  ln_write_row(ab0,ab1,ab2,ab3, denb, cs_b, gm_b, wgt + hd*DHEAD, out + rowb_off, base_d);
}

extern "C" void kernel_launch(void* const* d_in, const int* in_sizes, int n_in,
                              void* d_out, int out_size, void* d_ws, size_t ws_size,
                              hipStream_t stream) {
  (void)in_sizes; (void)n_in; (void)out_size; (void)ws_size;
  const float* q   = (const float*)d_in[0];
  const float* k   = (const float*)d_in[1];
  const float* v   = (const float*)d_in[2];
  const float* Wi  = (const float*)d_in[3];
  const float* bi  = (const float*)d_in[4];
  const float* Wf  = (const float*)d_in[5];
  const float* bf  = (const float*)d_in[6];
  const float* wgt = (const float*)d_in[7];
  float* out = (float*)d_out;
  float* ws  = (float*)d_ws;
  const int BNS = 2 * NHEAD * S_LEN;
  float* ig_pre = ws;
  float* fg_pre = ws + (size_t)BNS;
  float* cs     = ws + (size_t)2*BNS;
  float* gv     = ws + (size_t)3*BNS;
  float* gmaxs  = ws + (size_t)4*BNS;

  gates_kernel<<<1024, 256, 0, stream>>>(q, k, v, Wi, bi, Wf, bf, ig_pre, fg_pre);
  scan_kernel<<<16, 256, 0, stream>>>(ig_pre, fg_pre, cs, gv, gmaxs);
  mlstm_main<<<512, 256, 0, stream>>>(q, k, v, cs, gv, gmaxs, wgt, out);
}

// Round 2
// 163.920 us; speedup vs baseline: 6.0723x; 6.0723x over previous
//
#include <hip/hip_runtime.h>
#include <math.h>

#define S_LEN 2048
#define E_DIM 1024
#define NHEAD 8
#define DHEAD 128
#define KVB 32

typedef short bf16x8 __attribute__((ext_vector_type(8)));
typedef float f32x4 __attribute__((ext_vector_type(4)));
typedef unsigned int u32x4 __attribute__((ext_vector_type(4)));
typedef unsigned int u32x2 __attribute__((ext_vector_type(2)));

constexpr float RSQ_DH  = 0.08838834764831843f; // 1/sqrt(128)
constexpr float EPS_NORM = 1e-6f;
constexpr float LN_EPS_C = 1e-6f;

__device__ inline unsigned bfpair(float lo, float hi) {
  // pack two f32 -> two bf16 (RNE), lo in low 16 bits
  unsigned a = __builtin_bit_cast(unsigned, lo);
  unsigned b = __builtin_bit_cast(unsigned, hi);
  a = (a + 0x7fffu + ((a >> 16) & 1u)) >> 16;
  b = (b + 0x7fffu + ((b >> 16) & 1u)) >> 16;
  return a | (b << 16);
}

// ---------------- Kernel 1: gate preactivations (unchanged, verified) ----------------
__global__ __launch_bounds__(256) void gates_kernel(
    const float* __restrict__ q, const float* __restrict__ k, const float* __restrict__ v,
    const float* __restrict__ Wi, const float* __restrict__ bi,
    const float* __restrict__ Wf, const float* __restrict__ bf,
    float* __restrict__ ig_pre, float* __restrict__ fg_pre) {
  const int t = threadIdx.x;
  const int row0 = blockIdx.x * 4;
  float p[4][16];
#pragma unroll
  for (int rr = 0; rr < 4; ++rr)
#pragma unroll
    for (int c = 0; c < 16; ++c) p[rr][c] = 0.f;

  for (int i = 0; i < 12; ++i) {
    const int e = t + 256 * i;
    const float4 a0 = *(const float4*)(Wi + (size_t)e*8);
    const float4 a1 = *(const float4*)(Wi + (size_t)e*8 + 4);
    const float4 b0 = *(const float4*)(Wf + (size_t)e*8);
    const float4 b1 = *(const float4*)(Wf + (size_t)e*8 + 4);
    float wv[16] = {a0.x,a0.y,a0.z,a0.w, a1.x,a1.y,a1.z,a1.w,
                    b0.x,b0.y,b0.z,b0.w, b1.x,b1.y,b1.z,b1.w};
    const float* base; int eo;
    if (e < E_DIM)        { base = q; eo = e; }
    else if (e < 2*E_DIM) { base = k; eo = e - E_DIM; }
    else                  { base = v; eo = e - 2*E_DIM; }
#pragma unroll
    for (int rr = 0; rr < 4; ++rr) {
      const float x = base[(size_t)(row0+rr)*E_DIM + eo];
#pragma unroll
      for (int c = 0; c < 16; ++c) p[rr][c] += x * wv[c];
    }
  }
#pragma unroll
  for (int rr = 0; rr < 4; ++rr)
#pragma unroll
    for (int c = 0; c < 16; ++c) {
      float val = p[rr][c];
      val += __shfl_xor(val, 1);
      val += __shfl_xor(val, 2);
      val += __shfl_xor(val, 4);
      val += __shfl_xor(val, 8);
      val += __shfl_xor(val, 16);
      val += __shfl_xor(val, 32);
      p[rr][c] = val;
    }
  __shared__ float sred[4][4][16];
  const int wid = t >> 6, lane = t & 63;
  if (lane == 0) {
#pragma unroll
    for (int rr = 0; rr < 4; ++rr)
#pragma unroll
      for (int c = 0; c < 16; ++c) sred[wid][rr][c] = p[rr][c];
  }
  __syncthreads();
  if (t < 64) {
    const int rr = t >> 4, c = t & 15;
    float sum = sred[0][rr][c] + sred[1][rr][c] + sred[2][rr][c] + sred[3][rr][c];
    const int h = c & 7;
    const int row = row0 + rr;
    const int b = row / S_LEN, s = row % S_LEN;
    if (c < 8) ig_pre[((size_t)b*NHEAD + h)*S_LEN + s] = sum + bi[h];
    else       fg_pre[((size_t)b*NHEAD + h)*S_LEN + s] = sum + bf[h];
  }
}

// ---------------- Kernel 2: log-sigmoid + cumsum + prefix-max (unchanged) ----------------
__global__ __launch_bounds__(256) void scan_kernel(
    const float* __restrict__ ig_pre, const float* __restrict__ fg_pre,
    float* __restrict__ cs_out, float* __restrict__ g_out, float* __restrict__ gmax_out) {
  const int bhh = blockIdx.x;
  const int t = threadIdx.x;
  const size_t base = (size_t)bhh * S_LEN;
  float vals[8];
  float run = 0.f;
#pragma unroll
  for (int i = 0; i < 8; ++i) {
    const float x = fg_pre[base + t*8 + i];
    const float lf = fminf(x, 0.f) - log1pf(__expf(-fabsf(x)));
    run += lf;
    vals[i] = run;
  }
  __shared__ float sums[256];
  sums[t] = run;
  __syncthreads();
  for (int off = 1; off < 256; off <<= 1) {
    const float other = (t >= off) ? sums[t - off] : 0.f;
    __syncthreads();
    sums[t] += other;
    __syncthreads();
  }
  const float prefix = (t > 0) ? sums[t-1] : 0.f;
  float g_loc[8], gm_loc[8];
  float lmax = -3.4e38f;
#pragma unroll
  for (int i = 0; i < 8; ++i) {
    const float csv = vals[i] + prefix;
    vals[i] = csv;
    const float gg = ig_pre[base + t*8 + i] - csv;
    g_loc[i] = gg;
    lmax = fmaxf(lmax, gg);
    gm_loc[i] = lmax;
  }
  __shared__ float maxs[256];
  maxs[t] = lmax;
  __syncthreads();
  for (int off = 1; off < 256; off <<= 1) {
    const float other = (t >= off) ? maxs[t - off] : -3.4e38f;
    __syncthreads();
    maxs[t] = fmaxf(maxs[t], other);
    __syncthreads();
  }
  const float pmax = (t > 0) ? maxs[t-1] : -3.4e38f;
#pragma unroll
  for (int i = 0; i < 8; ++i) {
    cs_out[base + t*8 + i]   = vals[i];
    g_out[base + t*8 + i]    = g_loc[i];
    gmax_out[base + t*8 + i] = fmaxf(gm_loc[i], pmax);
  }
}

// ---------------- Kernel 3: MFMA flash-style gated attention + fused LN ----------------
// Block: one (b,h), 64 q-rows (interleaved by 4 across 4 waves), KV tiles of 32.
// S^T = mfma(A=K, B=Q)  -> lane holds w[i=lane&15][j=16*t2+4*qq+reg]
// PV  = mfma(A=w via LDS exchange, B=V^T in LDS)
__global__ __launch_bounds__(256) void mlstm_mfma(
    const float* __restrict__ q, const float* __restrict__ k, const float* __restrict__ v,
    const float* __restrict__ cs, const float* __restrict__ garr, const float* __restrict__ gmax,
    const float* __restrict__ wgt, float* __restrict__ out) {
  __shared__ unsigned short k_lds[32][136];   // K tile bf16, row-major, pad 8
  __shared__ unsigned int   vt_u32[128][20];  // V^T tile bf16 pairs: row=d, col=j/2, pad
  __shared__ unsigned int   xch[4][16][20];   // per-wave w exchange: [i][j/2], pad to 20
  __shared__ float          g_sh[KVB];

  const int bid = blockIdx.x;
  int qt;
  if (bid < 256) qt = 31 - (bid >> 4);   // heavy-first; CU c pairs qt + (31-qt)
  else           qt = (bid - 256) >> 4;
  const int bh = bid & 15;
  const int b = bh >> 3, h = bh & 7;
  const int t = threadIdx.x;
  const int w = t >> 6;
  const int l = t & 63;
  const int r = l & 15;
  const int qq = l >> 4;
  const size_t bhS = (size_t)bh * S_LEN;

  // lane's own q-row (i-local = r), rows interleaved by 4 so all waves reach diagonal
  const int gr = qt*64 + 4*r + w;
  const float gm_lane = gmax[bhS + gr];

  // Q fragments (B-operand): qfrag[c] holds Q[i=r][d = 32c + 8*qq + e]
  bf16x8 qfrag[4];
  {
    const float* qrow = q + ((size_t)b*S_LEN + gr)*E_DIM + h*DHEAD;
#pragma unroll
    for (int c = 0; c < 4; ++c) {
      const float4 f0 = *(const float4*)(qrow + 32*c + 8*qq);
      const float4 f1 = *(const float4*)(qrow + 32*c + 8*qq + 4);
      u32x4 u;
      u.x = bfpair(f0.x, f0.y); u.y = bfpair(f0.z, f0.w);
      u.z = bfpair(f1.x, f1.y); u.w = bfpair(f1.z, f1.w);
      qfrag[c] = __builtin_bit_cast(bf16x8, u);
    }
  }

  f32x4 o[8];
#pragma unroll
  for (int n = 0; n < 8; ++n) o[n] = (f32x4){0.f, 0.f, 0.f, 0.f};
  float den_p = 0.f;

  // staging assignments
  const int kj = t >> 3, ks = t & 7;     // K: row kj (32), 16-float seg ks (8)
  const int vjp = t & 15, vds = t >> 4;  // V: row-pair vjp (16), 8-float dseg vds (16)

  const int ntiles = 2*qt + 2;
  for (int jt = 0; jt < ntiles; ++jt) {
    const int j0 = jt * KVB;
    // ---- stage K tile (fp32 -> bf16, row-major) ----
    {
      const float* src = k + ((size_t)b*S_LEN + j0 + kj)*E_DIM + h*DHEAD + ks*16;
      float4 f0 = *(const float4*)(src);
      float4 f1 = *(const float4*)(src + 4);
      float4 f2 = *(const float4*)(src + 8);
      float4 f3 = *(const float4*)(src + 12);
      u32x4 ua, ub;
      ua.x = bfpair(f0.x,f0.y); ua.y = bfpair(f0.z,f0.w);
      ua.z = bfpair(f1.x,f1.y); ua.w = bfpair(f1.z,f1.w);
      ub.x = bfpair(f2.x,f2.y); ub.y = bfpair(f2.z,f2.w);
      ub.z = bfpair(f3.x,f3.y); ub.w = bfpair(f3.z,f3.w);
      *(u32x4*)&k_lds[kj][ks*16]     = ua;
      *(u32x4*)&k_lds[kj][ks*16 + 8] = ub;
    }
    // ---- stage V tile transposed (fp32 -> bf16 pairs along j) ----
    {
      const float* s0 = v + ((size_t)b*S_LEN + j0 + 2*vjp)*E_DIM + h*DHEAD + vds*8;
      const float* s1 = s0 + E_DIM;
      float4 a0 = *(const float4*)(s0);
      float4 a1 = *(const float4*)(s0 + 4);
      float4 b0 = *(const float4*)(s1);
      float4 b1 = *(const float4*)(s1 + 4);
      vt_u32[vds*8+0][vjp] = bfpair(a0.x, b0.x);
      vt_u32[vds*8+1][vjp] = bfpair(a0.y, b0.y);
      vt_u32[vds*8+2][vjp] = bfpair(a0.z, b0.z);
      vt_u32[vds*8+3][vjp] = bfpair(a0.w, b0.w);
      vt_u32[vds*8+4][vjp] = bfpair(a1.x, b1.x);
      vt_u32[vds*8+5][vjp] = bfpair(a1.y, b1.y);
      vt_u32[vds*8+6][vjp] = bfpair(a1.z, b1.z);
      vt_u32[vds*8+7][vjp] = bfpair(a1.w, b1.w);
    }
    if (t < KVB) g_sh[t] = garr[bhS + j0 + t];
    __syncthreads();

    // ---- S^T: D[j][i] = sum_d K[j][d] Q[i][d], accumulated over 4 d-chunks ----
    f32x4 st0 = {0,0,0,0}, st1 = {0,0,0,0};
#pragma unroll
    for (int c = 0; c < 4; ++c) {
      bf16x8 ka0 = *(const bf16x8*)&k_lds[r][32*c + 8*qq];
      bf16x8 ka1 = *(const bf16x8*)&k_lds[16 + r][32*c + 8*qq];
      st0 = __builtin_amdgcn_mfma_f32_16x16x32_bf16(ka0, qfrag[c], st0, 0, 0, 0);
      st1 = __builtin_amdgcn_mfma_f32_16x16x32_bf16(ka1, qfrag[c], st1, 0, 0, 0);
    }

    // ---- gated weights: w[i][j] = qk * exp(g[j]-gmax[i]) / sqrt(DH), causal mask ----
    const bool diag = (jt >= 2*qt);
    float wv0[4], wv1[4];
#pragma unroll
    for (int reg = 0; reg < 4; ++reg) {
      const int jl0 = 4*qq + reg, jl1 = 16 + 4*qq + reg;
      const float e0 = __expf(g_sh[jl0] - gm_lane);
      const float e1 = __expf(g_sh[jl1] - gm_lane);
      float w0 = st0[reg] * RSQ_DH * e0;
      float w1 = st1[reg] * RSQ_DH * e1;
      if (diag) {
        if (j0 + jl0 > gr) w0 = 0.f;
        if (j0 + jl1 > gr) w1 = 0.f;
      }
      wv0[reg] = w0; wv1[reg] = w1;
      den_p += w0 + w1;
    }

    // ---- in-wave LDS exchange: C-layout w -> A-fragment layout (bf16) ----
    u32x2 p0, p1;
    p0.x = bfpair(wv0[0], wv0[1]); p0.y = bfpair(wv0[2], wv0[3]);
    p1.x = bfpair(wv1[0], wv1[1]); p1.y = bfpair(wv1[2], wv1[3]);
    *(u32x2*)&xch[w][r][2*qq]     = p0;
    *(u32x2*)&xch[w][r][8 + 2*qq] = p1;
    __builtin_amdgcn_wave_barrier();
    bf16x8 pa = *(const bf16x8*)&xch[w][r][4*qq];
    __builtin_amdgcn_wave_barrier();

    // ---- PV: O[i][d] += sum_j w[i][j] V[j][d] ----
#pragma unroll
    for (int n = 0; n < 8; ++n) {
      bf16x8 vb = *(const bf16x8*)&vt_u32[16*n + r][4*qq];
      o[n] = __builtin_amdgcn_mfma_f32_16x16x32_bf16(pa, vb, o[n], 0, 0, 0);
    }
    __syncthreads();
  }

  // ---- epilogue: normalizer + per-head LayerNorm + store ----
  float den_f = den_p;
  den_f += __shfl_xor(den_f, 16);
  den_f += __shfl_xor(den_f, 32);   // all lanes: den for row i = r

  const float* wrow = wgt + h*DHEAD;
  float wv_n[8];
#pragma unroll
  for (int n = 0; n < 8; ++n) wv_n[n] = wrow[16*n + r];

#pragma unroll
  for (int reg = 0; reg < 4; ++reg) {
    const int iloc = 4*qq + reg;
    const float den_o = __shfl(den_f, iloc);
    const int grow = qt*64 + 4*iloc + w;
    const float csg = cs[bhS + grow];
    const float gmg = gmax[bhS + grow];
    const float norm = fmaxf(fabsf(den_o), __expf(-(csg + gmg))) + EPS_NORM;
    const float inv = 1.f / norm;
    float hv[8];
    float s1 = 0.f, s2 = 0.f;
#pragma unroll
    for (int n = 0; n < 8; ++n) {
      hv[n] = o[n][reg] * inv;
      s1 += hv[n]; s2 += hv[n]*hv[n];
    }
    s1 += __shfl_xor(s1, 1); s1 += __shfl_xor(s1, 2);
    s1 += __shfl_xor(s1, 4); s1 += __shfl_xor(s1, 8);
    s2 += __shfl_xor(s2, 1); s2 += __shfl_xor(s2, 2);
    s2 += __shfl_xor(s2, 4); s2 += __shfl_xor(s2, 8);
    const float mu  = s1 * (1.f/128.f);
    const float var = s2 * (1.f/128.f) - mu*mu;
    const float rstd = rsqrtf(var + LN_EPS_C);
    float* orow = out + ((size_t)b*S_LEN + grow)*E_DIM + h*DHEAD;
#pragma unroll
    for (int n = 0; n < 8; ++n)
      orow[16*n + r] = (hv[n] - mu) * rstd * wv_n[n];
  }
}

extern "C" void kernel_launch(void* const* d_in, const int* in_sizes, int n_in,
                              void* d_out, int out_size, void* d_ws, size_t ws_size,
                              hipStream_t stream) {
  (void)in_sizes; (void)n_in; (void)out_size; (void)ws_size;
  const float* q   = (const float*)d_in[0];
  const float* k   = (const float*)d_in[1];
  const float* v   = (const float*)d_in[2];
  const float* Wi  = (const float*)d_in[3];
  const float* bi  = (const float*)d_in[4];
  const float* Wf  = (const float*)d_in[5];
  const float* bf  = (const float*)d_in[6];
  const float* wgt = (const float*)d_in[7];
  float* out = (float*)d_out;
  float* ws  = (float*)d_ws;
  const int BNS = 2 * NHEAD * S_LEN;
  float* ig_pre = ws;
  float* fg_pre = ws + (size_t)BNS;
  float* cs     = ws + (size_t)2*BNS;
  float* gv     = ws + (size_t)3*BNS;
  float* gmaxs  = ws + (size_t)4*BNS;

  gates_kernel<<<1024, 256, 0, stream>>>(q, k, v, Wi, bi, Wf, bf, ig_pre, fg_pre);
  scan_kernel<<<16, 256, 0, stream>>>(ig_pre, fg_pre, cs, gv, gmaxs);
  mlstm_mfma<<<512, 256, 0, stream>>>(q, k, v, cs, gv, gmaxs, wgt, out);
}

// Round 4
// 117.394 us; speedup vs baseline: 8.4789x; 1.3963x over previous
//
#include <hip/hip_runtime.h>
#include <math.h>

#define S_LEN 2048
#define E_DIM 1024
#define NHEAD 8
#define DHEAD 128

typedef short bf16x8 __attribute__((ext_vector_type(8)));
typedef float f32x4 __attribute__((ext_vector_type(4)));
typedef unsigned int u32x4 __attribute__((ext_vector_type(4)));
typedef unsigned int u32x2 __attribute__((ext_vector_type(2)));

constexpr float RSQ_DH  = 0.08838834764831843f; // 1/sqrt(128)
constexpr float LNRSQ   = -2.4260151319598084f; // ln(1/sqrt(128))
constexpr float EPS_NORM = 1e-6f;
constexpr float LN_EPS_C = 1e-6f;

__device__ inline unsigned bfpair(float lo, float hi) {
  unsigned a = __builtin_bit_cast(unsigned, lo);
  unsigned b = __builtin_bit_cast(unsigned, hi);
  a = (a + 0x7fffu + ((a >> 16) & 1u)) >> 16;
  b = (b + 0x7fffu + ((b >> 16) & 1u)) >> 16;
  return a | (b << 16);
}

__device__ inline void gload_lds16(const void* g, void* lds) {
  __builtin_amdgcn_global_load_lds(
      (const __attribute__((address_space(1))) unsigned int*)g,
      (__attribute__((address_space(3))) unsigned int*)lds, 16, 0, 0);
}

// ---------------- Kernel 1: gates + bf16 K copy ----------------
__global__ __launch_bounds__(256) void gates_fused(
    const float* __restrict__ q, const float* __restrict__ k, const float* __restrict__ v,
    const float* __restrict__ Wi, const float* __restrict__ bi,
    const float* __restrict__ Wf, const float* __restrict__ bf,
    float* __restrict__ ig_pre, float* __restrict__ fg_pre,
    unsigned short* __restrict__ kb) {
  const int t = threadIdx.x;
  const int row0 = blockIdx.x * 4;
  const int b = row0 >> 11;
  const int s0 = row0 & 2047;
  float p[4][16];
#pragma unroll
  for (int rr = 0; rr < 4; ++rr)
#pragma unroll
    for (int c = 0; c < 16; ++c) p[rr][c] = 0.f;

#pragma unroll
  for (int i = 0; i < 3; ++i) {
    const float* base = (i == 0) ? q : (i == 1) ? k : v;
    float xs[4][4];
#pragma unroll
    for (int rr = 0; rr < 4; ++rr) {
      const float4 xv = *(const float4*)(base + (size_t)(row0 + rr) * E_DIM + t * 4);
      xs[rr][0] = xv.x; xs[rr][1] = xv.y; xs[rr][2] = xv.z; xs[rr][3] = xv.w;
    }
#pragma unroll
    for (int j = 0; j < 4; ++j) {
      const int ge = i * E_DIM + t * 4 + j;
      const float4 wiA = *(const float4*)(Wi + (size_t)ge * 8);
      const float4 wiB = *(const float4*)(Wi + (size_t)ge * 8 + 4);
      const float4 wfA = *(const float4*)(Wf + (size_t)ge * 8);
      const float4 wfB = *(const float4*)(Wf + (size_t)ge * 8 + 4);
      const float wv16[16] = {wiA.x, wiA.y, wiA.z, wiA.w, wiB.x, wiB.y, wiB.z, wiB.w,
                              wfA.x, wfA.y, wfA.z, wfA.w, wfB.x, wfB.y, wfB.z, wfB.w};
#pragma unroll
      for (int rr = 0; rr < 4; ++rr) {
        const float x = xs[rr][j];
#pragma unroll
        for (int c = 0; c < 16; ++c) p[rr][c] += x * wv16[c];
      }
    }
    if (i == 1 && kb != nullptr) {
      const int h = (t * 4) >> 7, d = (t * 4) & 127;
#pragma unroll
      for (int rr = 0; rr < 4; ++rr) {
        u32x2 pk;
        pk.x = bfpair(xs[rr][0], xs[rr][1]);
        pk.y = bfpair(xs[rr][2], xs[rr][3]);
        *(u32x2*)(kb + (((size_t)b * NHEAD + h) * S_LEN + (s0 + rr)) * DHEAD + d) = pk;
      }
    }
  }

#pragma unroll
  for (int rr = 0; rr < 4; ++rr)
#pragma unroll
    for (int c = 0; c < 16; ++c) {
      float val = p[rr][c];
      val += __shfl_xor(val, 1);
      val += __shfl_xor(val, 2);
      val += __shfl_xor(val, 4);
      val += __shfl_xor(val, 8);
      val += __shfl_xor(val, 16);
      val += __shfl_xor(val, 32);
      p[rr][c] = val;
    }
  __shared__ float sred[4][4][16];
  const int wid = t >> 6, lane = t & 63;
  if (lane == 0) {
#pragma unroll
    for (int rr = 0; rr < 4; ++rr)
#pragma unroll
      for (int c = 0; c < 16; ++c) sred[wid][rr][c] = p[rr][c];
  }
  __syncthreads();
  if (t < 64) {
    const int rr = t >> 4, c = t & 15;
    float sum = sred[0][rr][c] + sred[1][rr][c] + sred[2][rr][c] + sred[3][rr][c];
    const int h = c & 7;
    const int row = row0 + rr;
    const int bb = row / S_LEN, s = row % S_LEN;
    if (c < 8) ig_pre[((size_t)bb * NHEAD + h) * S_LEN + s] = sum + bi[h];
    else       fg_pre[((size_t)bb * NHEAD + h) * S_LEN + s] = sum + bf[h];
  }
}

// ---------------- Kernel 1b: V transpose to bf16 (bh, d, s), full-line writes ----------------
__global__ __launch_bounds__(256) void vtrans(const float* __restrict__ v,
                                              unsigned short* __restrict__ vtb) {
  __shared__ unsigned int tile[128][36];   // [d][s-pair], 16B-aligned rows
  const int bid = blockIdx.x;
  const int bh = bid >> 5, st = bid & 31;
  const int b = bh >> 3, h = bh & 7;
  const int s0 = st * 64;
  const int t = threadIdx.x;
#pragma unroll
  for (int i = 0; i < 4; ++i) {
    const int task = t + 256 * i;
    const int sp = task & 31, dq = task >> 5;
    const float* src = v + ((size_t)b * S_LEN + s0 + 2 * sp) * E_DIM + h * DHEAD + dq * 4;
    const float4 r0 = *(const float4*)(src);
    const float4 r1 = *(const float4*)(src + E_DIM);
    tile[dq * 4 + 0][sp] = bfpair(r0.x, r1.x);
    tile[dq * 4 + 1][sp] = bfpair(r0.y, r1.y);
    tile[dq * 4 + 2][sp] = bfpair(r0.z, r1.z);
    tile[dq * 4 + 3][sp] = bfpair(r0.w, r1.w);
  }
  __syncthreads();
#pragma unroll
  for (int i = 0; i < 2; ++i) {
    const int task = t + 256 * i;          // 0..511
    const int d = task >> 2, c4 = task & 3;
    u32x4 w0, w1;
    w0.x = tile[d][c4 * 8 + 0]; w0.y = tile[d][c4 * 8 + 1];
    w0.z = tile[d][c4 * 8 + 2]; w0.w = tile[d][c4 * 8 + 3];
    w1.x = tile[d][c4 * 8 + 4]; w1.y = tile[d][c4 * 8 + 5];
    w1.z = tile[d][c4 * 8 + 6]; w1.w = tile[d][c4 * 8 + 7];
    unsigned short* dst = vtb + ((size_t)bh * DHEAD + d) * S_LEN + s0 + c4 * 16;
    *(u32x4*)(dst)     = w0;
    *(u32x4*)(dst + 8) = w1;
  }
}

// ---------------- Kernel 2: log-sigmoid + cumsum + prefix-max ----------------
__global__ __launch_bounds__(256) void scan_kernel(
    const float* __restrict__ ig_pre, const float* __restrict__ fg_pre,
    float* __restrict__ cs_out, float* __restrict__ g_out, float* __restrict__ gmax_out,
    float g_add) {
  const int bhh = blockIdx.x;
  const int t = threadIdx.x;
  const size_t base = (size_t)bhh * S_LEN;
  float vals[8];
  float run = 0.f;
#pragma unroll
  for (int i = 0; i < 8; ++i) {
    const float x = fg_pre[base + t * 8 + i];
    const float lf = fminf(x, 0.f) - log1pf(__expf(-fabsf(x)));
    run += lf;
    vals[i] = run;
  }
  __shared__ float sums[256];
  sums[t] = run;
  __syncthreads();
  for (int off = 1; off < 256; off <<= 1) {
    const float other = (t >= off) ? sums[t - off] : 0.f;
    __syncthreads();
    sums[t] += other;
    __syncthreads();
  }
  const float prefix = (t > 0) ? sums[t - 1] : 0.f;
  float g_loc[8], gm_loc[8];
  float lmax = -3.4e38f;
#pragma unroll
  for (int i = 0; i < 8; ++i) {
    const float csv = vals[i] + prefix;
    vals[i] = csv;
    const float gg = ig_pre[base + t * 8 + i] - csv;
    g_loc[i] = gg;
    lmax = fmaxf(lmax, gg);
    gm_loc[i] = lmax;
  }
  __shared__ float maxs[256];
  maxs[t] = lmax;
  __syncthreads();
  for (int off = 1; off < 256; off <<= 1) {
    const float other = (t >= off) ? maxs[t - off] : -3.4e38f;
    __syncthreads();
    maxs[t] = fmaxf(maxs[t], other);
    __syncthreads();
  }
  const float pmax = (t > 0) ? maxs[t - 1] : -3.4e38f;
#pragma unroll
  for (int i = 0; i < 8; ++i) {
    cs_out[base + t * 8 + i]   = vals[i];
    g_out[base + t * 8 + i]    = g_loc[i] + g_add;
    gmax_out[base + t * 8 + i] = fmaxf(gm_loc[i], pmax);
  }
}

// ---------------- Kernel 3 (fast): 2-wave blocks, KVB=64, single-buffer, shfl exchange ----------------
// Block: (bh, qb) with 32 q-rows (interleaved by 2 across 2 waves). 1024 blocks.
__global__ __launch_bounds__(128) void mlstm_mfma3(
    const unsigned short* __restrict__ kb, const unsigned short* __restrict__ vtb,
    const float* __restrict__ q,
    const float* __restrict__ cs, const float* __restrict__ garr, const float* __restrict__ gmax,
    const float* __restrict__ wgt, float* __restrict__ out) {
  __shared__ __align__(16) unsigned char kbuf[16384];  // K tile 64x128 bf16 (swizzled)
  __shared__ __align__(16) unsigned char vbuf[16384];  // V^T tile 128x64 bf16 (swizzled)
  __shared__ float g_sh[64];

  const int bid = blockIdx.x;
  const int bh = 2 * (bid & 7) + ((bid >> 3) & 1);   // same-bh blocks on same XCD
  const int qb = 63 - (bid >> 4);                    // heavy-first
  const int b = bh >> 3, h = bh & 7;
  const int t = threadIdx.x;
  const int w = t >> 6;        // 0..1
  const int l = t & 63;
  const int r = l & 15;
  const int qq = l >> 4;
  const size_t bhS = (size_t)bh * S_LEN;

  const int gr = qb * 32 + 2 * r + w;
  const float gm_lane = gmax[bhS + gr];

  // Q fragment (B-operand): qfrag[c] = Q[i=r][d = 32c + 8qq + e]
  bf16x8 qfrag[4];
  {
    const float* qrow = q + ((size_t)b * S_LEN + gr) * E_DIM + h * DHEAD;
#pragma unroll
    for (int c = 0; c < 4; ++c) {
      const float4 f0 = *(const float4*)(qrow + 32 * c + 8 * qq);
      const float4 f1 = *(const float4*)(qrow + 32 * c + 8 * qq + 4);
      u32x4 u;
      u.x = bfpair(f0.x, f0.y); u.y = bfpair(f0.z, f0.w);
      u.z = bfpair(f1.x, f1.y); u.w = bfpair(f1.z, f1.w);
      qfrag[c] = __builtin_bit_cast(bf16x8, u);
    }
  }

  f32x4 o[8];
#pragma unroll
  for (int n = 0; n < 8; ++n) o[n] = (f32x4){0.f, 0.f, 0.f, 0.f};
  float den_p = 0.f;

  const unsigned short* kt = kb + bhS * DHEAD;
  const unsigned short* vt = vtb + (size_t)bh * DHEAD * S_LEN;

  const int ntiles = (qb >> 1) + 1;
  for (int jt = 0; jt < ntiles; ++jt) {
    const int j0 = jt * 64;
    // ---- stage K (swizzled source -> linear LDS) ----
#pragma unroll
    for (int a = 0; a < 8; ++a) {
      const int m = w * 512 + a * 64 + l;       // physical 16B unit
      const int u = m ^ ((m >> 4) & 7);         // logical unit (involution)
      const int j = u >> 4, seg = u & 15;
      gload_lds16(kt + ((size_t)(j0 + j)) * DHEAD + seg * 8,
                  &kbuf[(w * 512 + a * 64) * 16]);
    }
    // ---- stage V^T ----
#pragma unroll
    for (int a = 0; a < 8; ++a) {
      const int m = w * 512 + a * 64 + l;
      const int u = m ^ ((m >> 3) & 7);
      const int d = u >> 3, qv = u & 7;
      gload_lds16(vt + (size_t)d * S_LEN + j0 + qv * 8,
                  &vbuf[(w * 512 + a * 64) * 16]);
    }
    if (t < 64) g_sh[t] = garr[bhS + j0 + t];
    asm volatile("s_waitcnt vmcnt(0)" ::: "memory");
    __syncthreads();

    // ---- S^T: st[g] = K[16g..16g+15] . Q, over 4 d-chunks ----
    f32x4 st[4];
#pragma unroll
    for (int g = 0; g < 4; ++g) st[g] = (f32x4){0.f, 0.f, 0.f, 0.f};
#pragma unroll
    for (int c = 0; c < 4; ++c) {
#pragma unroll
      for (int g = 0; g < 4; ++g) {
        const int u = ((16 * g + r) * 16 + 4 * c + qq) ^ (r & 7);
        bf16x8 ka = *(const bf16x8*)&kbuf[u * 16];
        st[g] = __builtin_amdgcn_mfma_f32_16x16x32_bf16(ka, qfrag[c], st[g], 0, 0, 0);
      }
    }

    // ---- gated weights w[i=r][j=16g+4qq+m] (scale folded into garr) ----
    const bool diag = (jt == ntiles - 1);
    unsigned P[4][2];
#pragma unroll
    for (int g = 0; g < 4; ++g) {
      float wv[4];
#pragma unroll
      for (int m = 0; m < 4; ++m) {
        const int jl = 16 * g + 4 * qq + m;
        float ww = st[g][m] * __expf(g_sh[jl] - gm_lane);
        if (diag && (j0 + jl > gr)) ww = 0.f;
        wv[m] = ww;
        den_p += ww;
      }
      P[g][0] = bfpair(wv[0], wv[1]);
      P[g][1] = bfpair(wv[2], wv[3]);
    }

    // ---- in-register exchange: C-layout -> A-fragments (j 0..31 and 32..63) ----
    unsigned A0[4], A1[4];
#pragma unroll
    for (int m = 0; m < 4; ++m) {
      const int srcl = r + 16 * (2 * (qq & 1) + (m >> 1));
      const unsigned x0 = (unsigned)__shfl((int)P[0][m & 1], srcl);
      const unsigned x1 = (unsigned)__shfl((int)P[1][m & 1], srcl);
      const unsigned x2 = (unsigned)__shfl((int)P[2][m & 1], srcl);
      const unsigned x3 = (unsigned)__shfl((int)P[3][m & 1], srcl);
      A0[m] = (qq < 2) ? x0 : x1;
      A1[m] = (qq < 2) ? x2 : x3;
    }
    u32x4 ua0, ua1;
    ua0.x = A0[0]; ua0.y = A0[1]; ua0.z = A0[2]; ua0.w = A0[3];
    ua1.x = A1[0]; ua1.y = A1[1]; ua1.z = A1[2]; ua1.w = A1[3];
    const bf16x8 pa0 = __builtin_bit_cast(bf16x8, ua0);
    const bf16x8 pa1 = __builtin_bit_cast(bf16x8, ua1);

    // ---- PV: O[i][d] += w . V over two 32-j chunks ----
#pragma unroll
    for (int n = 0; n < 8; ++n) {
      const int d = 16 * n + r;
      const int u0 = (d * 8 + qq)     ^ (d & 7);
      const int u1 = (d * 8 + 4 + qq) ^ (d & 7);
      bf16x8 vb0 = *(const bf16x8*)&vbuf[u0 * 16];
      bf16x8 vb1 = *(const bf16x8*)&vbuf[u1 * 16];
      o[n] = __builtin_amdgcn_mfma_f32_16x16x32_bf16(pa0, vb0, o[n], 0, 0, 0);
      o[n] = __builtin_amdgcn_mfma_f32_16x16x32_bf16(pa1, vb1, o[n], 0, 0, 0);
    }
    __syncthreads();
  }

  // ---- epilogue: normalizer + per-head LayerNorm + store ----
  float den_f = den_p;
  den_f += __shfl_xor(den_f, 16);
  den_f += __shfl_xor(den_f, 32);

  const float* wrow = wgt + h * DHEAD;
  float wv_n[8];
#pragma unroll
  for (int n = 0; n < 8; ++n) wv_n[n] = wrow[16 * n + r];

#pragma unroll
  for (int m = 0; m < 4; ++m) {
    const int iloc = 4 * qq + m;
    const float den_o = __shfl(den_f, iloc);
    const int grow = qb * 32 + 2 * iloc + w;
    const float csg = cs[bhS + grow];
    const float gmg = gmax[bhS + grow];
    const float norm = fmaxf(fabsf(den_o), __expf(-(csg + gmg))) + EPS_NORM;
    const float inv = 1.f / norm;
    float hv[8];
    float s1 = 0.f, s2 = 0.f;
#pragma unroll
    for (int n = 0; n < 8; ++n) {
      hv[n] = o[n][m] * inv;
      s1 += hv[n]; s2 += hv[n] * hv[n];
    }
    s1 += __shfl_xor(s1, 1); s1 += __shfl_xor(s1, 2);
    s1 += __shfl_xor(s1, 4); s1 += __shfl_xor(s1, 8);
    s2 += __shfl_xor(s2, 1); s2 += __shfl_xor(s2, 2);
    s2 += __shfl_xor(s2, 4); s2 += __shfl_xor(s2, 8);
    const float mu  = s1 * (1.f / 128.f);
    const float var = s2 * (1.f / 128.f) - mu * mu;
    const float rstd = rsqrtf(var + LN_EPS_C);
    float* orow = out + ((size_t)b * S_LEN + grow) * E_DIM + h * DHEAD;
#pragma unroll
    for (int n = 0; n < 8; ++n)
      orow[16 * n + r] = (hv[n] - mu) * rstd * wv_n[n];
  }
}

// ---------------- Kernel 3 (fallback, round-2 verified): fp32 staged in-loop ----------------
__global__ __launch_bounds__(256) void mlstm_mfma(
    const float* __restrict__ q, const float* __restrict__ k, const float* __restrict__ v,
    const float* __restrict__ cs, const float* __restrict__ garr, const float* __restrict__ gmax,
    const float* __restrict__ wgt, float* __restrict__ out) {
  __shared__ unsigned short k_lds[32][136];
  __shared__ unsigned int   vt_u32[128][20];
  __shared__ unsigned int   xch[4][16][20];
  __shared__ float          g_sh[32];

  const int bid = blockIdx.x;
  int qt;
  if (bid < 256) qt = 31 - (bid >> 4);
  else           qt = (bid - 256) >> 4;
  const int bh = bid & 15;
  const int b = bh >> 3, h = bh & 7;
  const int t = threadIdx.x;
  const int w = t >> 6;
  const int l = t & 63;
  const int r = l & 15;
  const int qq = l >> 4;
  const size_t bhS = (size_t)bh * S_LEN;

  const int gr = qt * 64 + 4 * r + w;
  const float gm_lane = gmax[bhS + gr];

  bf16x8 qfrag[4];
  {
    const float* qrow = q + ((size_t)b * S_LEN + gr) * E_DIM + h * DHEAD;
#pragma unroll
    for (int c = 0; c < 4; ++c) {
      const float4 f0 = *(const float4*)(qrow + 32 * c + 8 * qq);
      const float4 f1 = *(const float4*)(qrow + 32 * c + 8 * qq + 4);
      u32x4 u;
      u.x = bfpair(f0.x, f0.y); u.y = bfpair(f0.z, f0.w);
      u.z = bfpair(f1.x, f1.y); u.w = bfpair(f1.z, f1.w);
      qfrag[c] = __builtin_bit_cast(bf16x8, u);
    }
  }

  f32x4 o[8];
#pragma unroll
  for (int n = 0; n < 8; ++n) o[n] = (f32x4){0.f, 0.f, 0.f, 0.f};
  float den_p = 0.f;

  const int kj = t >> 3, ks = t & 7;
  const int vjp = t & 15, vds = t >> 4;

  const int ntiles = 2 * qt + 2;
  for (int jt = 0; jt < ntiles; ++jt) {
    const int j0 = jt * 32;
    {
      const float* src = k + ((size_t)b * S_LEN + j0 + kj) * E_DIM + h * DHEAD + ks * 16;
      float4 f0 = *(const float4*)(src);
      float4 f1 = *(const float4*)(src + 4);
      float4 f2 = *(const float4*)(src + 8);
      float4 f3 = *(const float4*)(src + 12);
      u32x4 ua, ub;
      ua.x = bfpair(f0.x, f0.y); ua.y = bfpair(f0.z, f0.w);
      ua.z = bfpair(f1.x, f1.y); ua.w = bfpair(f1.z, f1.w);
      ub.x = bfpair(f2.x, f2.y); ub.y = bfpair(f2.z, f2.w);
      ub.z = bfpair(f3.x, f3.y); ub.w = bfpair(f3.z, f3.w);
      *(u32x4*)&k_lds[kj][ks * 16]     = ua;
      *(u32x4*)&k_lds[kj][ks * 16 + 8] = ub;
    }
    {
      const float* s0 = v + ((size_t)b * S_LEN + j0 + 2 * vjp) * E_DIM + h * DHEAD + vds * 8;
      const float* s1 = s0 + E_DIM;
      float4 a0 = *(const float4*)(s0);
      float4 a1 = *(const float4*)(s0 + 4);
      float4 b0 = *(const float4*)(s1);
      float4 b1 = *(const float4*)(s1 + 4);
      vt_u32[vds * 8 + 0][vjp] = bfpair(a0.x, b0.x);
      vt_u32[vds * 8 + 1][vjp] = bfpair(a0.y, b0.y);
      vt_u32[vds * 8 + 2][vjp] = bfpair(a0.z, b0.z);
      vt_u32[vds * 8 + 3][vjp] = bfpair(a0.w, b0.w);
      vt_u32[vds * 8 + 4][vjp] = bfpair(a1.x, b1.x);
      vt_u32[vds * 8 + 5][vjp] = bfpair(a1.y, b1.y);
      vt_u32[vds * 8 + 6][vjp] = bfpair(a1.z, b1.z);
      vt_u32[vds * 8 + 7][vjp] = bfpair(a1.w, b1.w);
    }
    if (t < 32) g_sh[t] = garr[bhS + j0 + t];
    __syncthreads();

    f32x4 st0 = {0, 0, 0, 0}, st1 = {0, 0, 0, 0};
#pragma unroll
    for (int c = 0; c < 4; ++c) {
      bf16x8 ka0 = *(const bf16x8*)&k_lds[r][32 * c + 8 * qq];
      bf16x8 ka1 = *(const bf16x8*)&k_lds[16 + r][32 * c + 8 * qq];
      st0 = __builtin_amdgcn_mfma_f32_16x16x32_bf16(ka0, qfrag[c], st0, 0, 0, 0);
      st1 = __builtin_amdgcn_mfma_f32_16x16x32_bf16(ka1, qfrag[c], st1, 0, 0, 0);
    }

    const bool diag = (jt >= 2 * qt);
    float wv0[4], wv1[4];
#pragma unroll
    for (int reg = 0; reg < 4; ++reg) {
      const int jl0 = 4 * qq + reg, jl1 = 16 + 4 * qq + reg;
      const float e0 = __expf(g_sh[jl0] - gm_lane);
      const float e1 = __expf(g_sh[jl1] - gm_lane);
      float w0 = st0[reg] * RSQ_DH * e0;
      float w1 = st1[reg] * RSQ_DH * e1;
      if (diag) {
        if (j0 + jl0 > gr) w0 = 0.f;
        if (j0 + jl1 > gr) w1 = 0.f;
      }
      wv0[reg] = w0; wv1[reg] = w1;
      den_p += w0 + w1;
    }

    u32x2 p0, p1;
    p0.x = bfpair(wv0[0], wv0[1]); p0.y = bfpair(wv0[2], wv0[3]);
    p1.x = bfpair(wv1[0], wv1[1]); p1.y = bfpair(wv1[2], wv1[3]);
    *(u32x2*)&xch[w][r][2 * qq]     = p0;
    *(u32x2*)&xch[w][r][8 + 2 * qq] = p1;
    __builtin_amdgcn_wave_barrier();
    bf16x8 pa = *(const bf16x8*)&xch[w][r][4 * qq];
    __builtin_amdgcn_wave_barrier();

#pragma unroll
    for (int n = 0; n < 8; ++n) {
      bf16x8 vb = *(const bf16x8*)&vt_u32[16 * n + r][4 * qq];
      o[n] = __builtin_amdgcn_mfma_f32_16x16x32_bf16(pa, vb, o[n], 0, 0, 0);
    }
    __syncthreads();
  }

  float den_f = den_p;
  den_f += __shfl_xor(den_f, 16);
  den_f += __shfl_xor(den_f, 32);

  const float* wrow = wgt + h * DHEAD;
  float wv_n[8];
#pragma unroll
  for (int n = 0; n < 8; ++n) wv_n[n] = wrow[16 * n + r];

#pragma unroll
  for (int reg = 0; reg < 4; ++reg) {
    const int iloc = 4 * qq + reg;
    const float den_o = __shfl(den_f, iloc);
    const int grow = qt * 64 + 4 * iloc + w;
    const float csg = cs[bhS + grow];
    const float gmg = gmax[bhS + grow];
    const float norm = fmaxf(fabsf(den_o), __expf(-(csg + gmg))) + EPS_NORM;
    const float inv = 1.f / norm;
    float hv[8];
    float s1 = 0.f, s2 = 0.f;
#pragma unroll
    for (int n = 0; n < 8; ++n) {
      hv[n] = o[n][reg] * inv;
      s1 += hv[n]; s2 += hv[n] * hv[n];
    }
    s1 += __shfl_xor(s1, 1); s1 += __shfl_xor(s1, 2);
    s1 += __shfl_xor(s1, 4); s1 += __shfl_xor(s1, 8);
    s2 += __shfl_xor(s2, 1); s2 += __shfl_xor(s2, 2);
    s2 += __shfl_xor(s2, 4); s2 += __shfl_xor(s2, 8);
    const float mu  = s1 * (1.f / 128.f);
    const float var = s2 * (1.f / 128.f) - mu * mu;
    const float rstd = rsqrtf(var + LN_EPS_C);
    float* orow = out + ((size_t)b * S_LEN + grow) * E_DIM + h * DHEAD;
#pragma unroll
    for (int n = 0; n < 8; ++n)
      orow[16 * n + r] = (hv[n] - mu) * rstd * wv_n[n];
  }
}

extern "C" void kernel_launch(void* const* d_in, const int* in_sizes, int n_in,
                              void* d_out, int out_size, void* d_ws, size_t ws_size,
                              hipStream_t stream) {
  (void)in_sizes; (void)n_in; (void)out_size;
  const float* q   = (const float*)d_in[0];
  const float* k   = (const float*)d_in[1];
  const float* v   = (const float*)d_in[2];
  const float* Wi  = (const float*)d_in[3];
  const float* bi  = (const float*)d_in[4];
  const float* Wf  = (const float*)d_in[5];
  const float* bf  = (const float*)d_in[6];
  const float* wgt = (const float*)d_in[7];
  float* out = (float*)d_out;
  float* ws  = (float*)d_ws;
  const int BNS = 2 * NHEAD * S_LEN;              // 32768
  float* ig_pre = ws;
  float* fg_pre = ws + (size_t)BNS;
  float* cs     = ws + (size_t)2 * BNS;
  float* gv     = ws + (size_t)3 * BNS;
  float* gmaxs  = ws + (size_t)4 * BNS;
  unsigned short* kb  = (unsigned short*)(ws + (size_t)5 * BNS);
  unsigned short* vtb = kb + (size_t)16 * S_LEN * DHEAD;

  const size_t need = (size_t)5 * BNS * 4 + (size_t)2 * 16 * S_LEN * DHEAD * 2;

  if (ws_size >= need) {
    gates_fused<<<1024, 256, 0, stream>>>(q, k, v, Wi, bi, Wf, bf, ig_pre, fg_pre, kb);
    vtrans<<<512, 256, 0, stream>>>(v, vtb);
    scan_kernel<<<16, 256, 0, stream>>>(ig_pre, fg_pre, cs, gv, gmaxs, LNRSQ);
    mlstm_mfma3<<<1024, 128, 0, stream>>>(kb, vtb, q, cs, gv, gmaxs, wgt, out);
  } else {
    gates_fused<<<1024, 256, 0, stream>>>(q, k, v, Wi, bi, Wf, bf, ig_pre, fg_pre, nullptr);
    scan_kernel<<<16, 256, 0, stream>>>(ig_pre, fg_pre, cs, gv, gmaxs, 0.0f);
    mlstm_mfma<<<512, 256, 0, stream>>>(q, k, v, cs, gv, gmaxs, wgt, out);
  }
}

// Round 6
// 116.867 us; speedup vs baseline: 8.5171x; 1.0045x over previous
//
#include <hip/hip_runtime.h>
#include <math.h>

#define S_LEN 2048
#define E_DIM 1024
#define NHEAD 8
#define DHEAD 128

typedef short bf16x8 __attribute__((ext_vector_type(8)));
typedef float f32x4 __attribute__((ext_vector_type(4)));
typedef unsigned int u32x4 __attribute__((ext_vector_type(4)));
typedef unsigned int u32x2 __attribute__((ext_vector_type(2)));

constexpr float RSQ_DH  = 0.08838834764831843f; // 1/sqrt(128)
constexpr float LNRSQ   = -2.4260151319598084f; // ln(1/sqrt(128))
constexpr float EPS_NORM = 1e-6f;
constexpr float LN_EPS_C = 1e-6f;

__device__ inline unsigned bfpair(float lo, float hi) {
  unsigned a = __builtin_bit_cast(unsigned, lo);
  unsigned b = __builtin_bit_cast(unsigned, hi);
  a = (a + 0x7fffu + ((a >> 16) & 1u)) >> 16;
  b = (b + 0x7fffu + ((b >> 16) & 1u)) >> 16;
  return a | (b << 16);
}

__device__ inline void gload_lds16(const void* g, void* lds) {
  __builtin_amdgcn_global_load_lds(
      (const __attribute__((address_space(1))) unsigned int*)g,
      (__attribute__((address_space(3))) unsigned int*)lds, 16, 0, 0);
}
__device__ inline void gload_lds4(const void* g, void* lds) {
  __builtin_amdgcn_global_load_lds(
      (const __attribute__((address_space(1))) unsigned int*)g,
      (__attribute__((address_space(3))) unsigned int*)lds, 4, 0, 0);
}

// ---------------- Kernel 1: gates (8 rows/block) + bf16 K copy ----------------
__global__ __launch_bounds__(256) void gates_fused(
    const float* __restrict__ q, const float* __restrict__ k, const float* __restrict__ v,
    const float* __restrict__ Wi, const float* __restrict__ bi,
    const float* __restrict__ Wf, const float* __restrict__ bf,
    float* __restrict__ ig_pre, float* __restrict__ fg_pre,
    unsigned short* __restrict__ kb) {
  const int t = threadIdx.x;
  const int row0 = blockIdx.x * 8;
  const int b = row0 >> 11;
  const int s0 = row0 & 2047;
  float p[8][16];
#pragma unroll
  for (int rr = 0; rr < 8; ++rr)
#pragma unroll
    for (int c = 0; c < 16; ++c) p[rr][c] = 0.f;

#pragma unroll
  for (int i = 0; i < 3; ++i) {
    const float* base = (i == 0) ? q : (i == 1) ? k : v;
    float xs[8][4];
#pragma unroll
    for (int rr = 0; rr < 8; ++rr) {
      const float4 xv = *(const float4*)(base + (size_t)(row0 + rr) * E_DIM + t * 4);
      xs[rr][0] = xv.x; xs[rr][1] = xv.y; xs[rr][2] = xv.z; xs[rr][3] = xv.w;
    }
#pragma unroll
    for (int j = 0; j < 4; ++j) {
      const int ge = i * E_DIM + t * 4 + j;
      const float4 wiA = *(const float4*)(Wi + (size_t)ge * 8);
      const float4 wiB = *(const float4*)(Wi + (size_t)ge * 8 + 4);
      const float4 wfA = *(const float4*)(Wf + (size_t)ge * 8);
      const float4 wfB = *(const float4*)(Wf + (size_t)ge * 8 + 4);
      const float wv16[16] = {wiA.x, wiA.y, wiA.z, wiA.w, wiB.x, wiB.y, wiB.z, wiB.w,
                              wfA.x, wfA.y, wfA.z, wfA.w, wfB.x, wfB.y, wfB.z, wfB.w};
#pragma unroll
      for (int rr = 0; rr < 8; ++rr) {
        const float x = xs[rr][j];
#pragma unroll
        for (int c = 0; c < 16; ++c) p[rr][c] += x * wv16[c];
      }
    }
    if (i == 1 && kb != nullptr) {
      const int h = (t * 4) >> 7, d = (t * 4) & 127;
#pragma unroll
      for (int rr = 0; rr < 8; ++rr) {
        u32x2 pk;
        pk.x = bfpair(xs[rr][0], xs[rr][1]);
        pk.y = bfpair(xs[rr][2], xs[rr][3]);
        *(u32x2*)(kb + (((size_t)b * NHEAD + h) * S_LEN + (s0 + rr)) * DHEAD + d) = pk;
      }
    }
  }

#pragma unroll
  for (int rr = 0; rr < 8; ++rr)
#pragma unroll
    for (int c = 0; c < 16; ++c) {
      float val = p[rr][c];
      val += __shfl_xor(val, 1);
      val += __shfl_xor(val, 2);
      val += __shfl_xor(val, 4);
      val += __shfl_xor(val, 8);
      val += __shfl_xor(val, 16);
      val += __shfl_xor(val, 32);
      p[rr][c] = val;
    }
  __shared__ float sred[4][8][16];
  const int wid = t >> 6, lane = t & 63;
  if (lane == 0) {
#pragma unroll
    for (int rr = 0; rr < 8; ++rr)
#pragma unroll
      for (int c = 0; c < 16; ++c) sred[wid][rr][c] = p[rr][c];
  }
  __syncthreads();
  if (t < 128) {
    const int rr = t >> 4, c = t & 15;
    float sum = sred[0][rr][c] + sred[1][rr][c] + sred[2][rr][c] + sred[3][rr][c];
    const int h = c & 7;
    const int row = row0 + rr;
    const int bb = row / S_LEN, s = row % S_LEN;
    if (c < 8) ig_pre[((size_t)bb * NHEAD + h) * S_LEN + s] = sum + bi[h];
    else       fg_pre[((size_t)bb * NHEAD + h) * S_LEN + s] = sum + bf[h];
  }
}

// ---------------- Kernel 1b: V transpose to bf16 (bh, d, s) ----------------
__global__ __launch_bounds__(256) void vtrans(const float* __restrict__ v,
                                              unsigned short* __restrict__ vtb) {
  __shared__ unsigned int tile[128][36];
  const int bid = blockIdx.x;
  const int bh = bid >> 5, st = bid & 31;
  const int b = bh >> 3, h = bh & 7;
  const int s0 = st * 64;
  const int t = threadIdx.x;
#pragma unroll
  for (int i = 0; i < 4; ++i) {
    const int task = t + 256 * i;
    const int sp = task & 31, dq = task >> 5;
    const float* src = v + ((size_t)b * S_LEN + s0 + 2 * sp) * E_DIM + h * DHEAD + dq * 4;
    const float4 r0 = *(const float4*)(src);
    const float4 r1 = *(const float4*)(src + E_DIM);
    tile[dq * 4 + 0][sp] = bfpair(r0.x, r1.x);
    tile[dq * 4 + 1][sp] = bfpair(r0.y, r1.y);
    tile[dq * 4 + 2][sp] = bfpair(r0.z, r1.z);
    tile[dq * 4 + 3][sp] = bfpair(r0.w, r1.w);
  }
  __syncthreads();
#pragma unroll
  for (int i = 0; i < 2; ++i) {
    const int task = t + 256 * i;
    const int d = task >> 2, c4 = task & 3;
    u32x4 w0, w1;
    w0.x = tile[d][c4 * 8 + 0]; w0.y = tile[d][c4 * 8 + 1];
    w0.z = tile[d][c4 * 8 + 2]; w0.w = tile[d][c4 * 8 + 3];
    w1.x = tile[d][c4 * 8 + 4]; w1.y = tile[d][c4 * 8 + 5];
    w1.z = tile[d][c4 * 8 + 6]; w1.w = tile[d][c4 * 8 + 7];
    unsigned short* dst = vtb + ((size_t)bh * DHEAD + d) * S_LEN + s0 + c4 * 16;
    *(u32x4*)(dst)     = w0;
    *(u32x4*)(dst + 8) = w1;
  }
}

// ---------------- Kernel 2: log-sigmoid + cumsum + prefix-max ----------------
__global__ __launch_bounds__(256) void scan_kernel(
    const float* __restrict__ ig_pre, const float* __restrict__ fg_pre,
    float* __restrict__ cs_out, float* __restrict__ g_out, float* __restrict__ gmax_out,
    float g_add) {
  const int bhh = blockIdx.x;
  const int t = threadIdx.x;
  const size_t base = (size_t)bhh * S_LEN;
  float vals[8];
  float run = 0.f;
#pragma unroll
  for (int i = 0; i < 8; ++i) {
    const float x = fg_pre[base + t * 8 + i];
    const float lf = fminf(x, 0.f) - log1pf(__expf(-fabsf(x)));
    run += lf;
    vals[i] = run;
  }
  __shared__ float sums[256];
  sums[t] = run;
  __syncthreads();
  for (int off = 1; off < 256; off <<= 1) {
    const float other = (t >= off) ? sums[t - off] : 0.f;
    __syncthreads();
    sums[t] += other;
    __syncthreads();
  }
  const float prefix = (t > 0) ? sums[t - 1] : 0.f;
  float g_loc[8], gm_loc[8];
  float lmax = -3.4e38f;
#pragma unroll
  for (int i = 0; i < 8; ++i) {
    const float csv = vals[i] + prefix;
    vals[i] = csv;
    const float gg = ig_pre[base + t * 8 + i] - csv;
    g_loc[i] = gg;
    lmax = fmaxf(lmax, gg);
    gm_loc[i] = lmax;
  }
  __shared__ float maxs[256];
  maxs[t] = lmax;
  __syncthreads();
  for (int off = 1; off < 256; off <<= 1) {
    const float other = (t >= off) ? maxs[t - off] : -3.4e38f;
    __syncthreads();
    maxs[t] = fmaxf(maxs[t], other);
    __syncthreads();
  }
  const float pmax = (t > 0) ? maxs[t - 1] : -3.4e38f;
#pragma unroll
  for (int i = 0; i < 8; ++i) {
    cs_out[base + t * 8 + i]   = vals[i];
    g_out[base + t * 8 + i]    = g_loc[i] + g_add;
    gmax_out[base + t * 8 + i] = fmaxf(gm_loc[i], pmax);
  }
}

// ---------------- Kernel 3 (fast): dbuf + counted vmcnt pipeline ----------------
// Block: (bh, qb), 32 q-rows, 2 waves. Per stage: 17 vmem ops/wave (8 K + 8 V + 1 g).
__global__ __launch_bounds__(128) void mlstm_mfma3(
    const unsigned short* __restrict__ kb, const unsigned short* __restrict__ vtb,
    const float* __restrict__ q,
    const float* __restrict__ cs, const float* __restrict__ garr, const float* __restrict__ gmax,
    const float* __restrict__ wgt, float* __restrict__ out) {
  __shared__ __align__(16) unsigned char kbuf[2][16384];  // K tile 64x128 bf16 (swizzled)
  __shared__ __align__(16) unsigned char vbuf[2][16384];  // V^T tile 128x64 bf16 (swizzled)
  __shared__ float g_sh[2][64];

  const int bid = blockIdx.x;
  const int bh = 2 * (bid & 7) + ((bid >> 3) & 1);   // same-bh blocks on same XCD
  const int qb = 63 - (bid >> 4);                    // heavy-first
  const int b = bh >> 3, h = bh & 7;
  const int t = threadIdx.x;
  const int w = t >> 6;        // 0..1
  const int l = t & 63;
  const int r = l & 15;
  const int qq = l >> 4;
  const size_t bhS = (size_t)bh * S_LEN;

  const int gr = qb * 32 + 2 * r + w;
  const float gm_lane = gmax[bhS + gr];

  // Q fragment (B-operand): qfrag[c] = Q[i=r][d = 32c + 8qq + e]
  bf16x8 qfrag[4];
  {
    const float* qrow = q + ((size_t)b * S_LEN + gr) * E_DIM + h * DHEAD;
#pragma unroll
    for (int c = 0; c < 4; ++c) {
      const float4 f0 = *(const float4*)(qrow + 32 * c + 8 * qq);
      const float4 f1 = *(const float4*)(qrow + 32 * c + 8 * qq + 4);
      u32x4 u;
      u.x = bfpair(f0.x, f0.y); u.y = bfpair(f0.z, f0.w);
      u.z = bfpair(f1.x, f1.y); u.w = bfpair(f1.z, f1.w);
      qfrag[c] = __builtin_bit_cast(bf16x8, u);
    }
  }

  f32x4 o[8];
#pragma unroll
  for (int n = 0; n < 8; ++n) o[n] = (f32x4){0.f, 0.f, 0.f, 0.f};
  float den_p = 0.f;

  const unsigned short* kt = kb + bhS * DHEAD;
  const unsigned short* vt = vtb + (size_t)bh * DHEAD * S_LEN;

  const int ntiles = (qb >> 1) + 1;

  // ---- stage tile jt_ into buffer bufi: exactly 17 vmem ops per wave ----
  auto stage = [&](int jt_, int bufi) {
    const int j0 = jt_ * 64;
#pragma unroll
    for (int a = 0; a < 8; ++a) {
      const int m = w * 512 + a * 64 + l;       // physical 16B unit
      const int u = m ^ ((m >> 4) & 7);         // logical unit (involution)
      const int j = u >> 4, seg = u & 15;
      gload_lds16(kt + ((size_t)(j0 + j)) * DHEAD + seg * 8,
                  &kbuf[bufi][(w * 512 + a * 64) * 16]);
    }
#pragma unroll
    for (int a = 0; a < 8; ++a) {
      const int m = w * 512 + a * 64 + l;
      const int u = m ^ ((m >> 3) & 7);
      const int d = u >> 3, qv = u & 7;
      gload_lds16(vt + (size_t)d * S_LEN + j0 + qv * 8,
                  &vbuf[bufi][(w * 512 + a * 64) * 16]);
    }
    // g tile: 64 floats; PER-LANE global source (lane l -> g[j0+l]), uniform LDS base.
    gload_lds4(garr + bhS + j0 + l, &g_sh[bufi][0]);
  };

  stage(0, 0);

  for (int jt = 0; jt < ntiles; ++jt) {
    const int cur = jt & 1;
    if (jt + 1 < ntiles) {
      stage(jt + 1, cur ^ 1);
      asm volatile("s_waitcnt vmcnt(17)" ::: "memory");  // tile jt drained, jt+1 in flight
    } else {
      asm volatile("s_waitcnt vmcnt(0)" ::: "memory");
    }
    __builtin_amdgcn_sched_barrier(0);
    __syncthreads();
    __builtin_amdgcn_s_setprio(1);
    const int j0 = jt * 64;

    // ---- S^T: st[g] = K[16g..16g+15] . Q, over 4 d-chunks ----
    f32x4 st[4];
#pragma unroll
    for (int g = 0; g < 4; ++g) st[g] = (f32x4){0.f, 0.f, 0.f, 0.f};
#pragma unroll
    for (int c = 0; c < 4; ++c) {
#pragma unroll
      for (int g = 0; g < 4; ++g) {
        const int u = ((16 * g + r) * 16 + 4 * c + qq) ^ (r & 7);
        bf16x8 ka = *(const bf16x8*)&kbuf[cur][u * 16];
        st[g] = __builtin_amdgcn_mfma_f32_16x16x32_bf16(ka, qfrag[c], st[g], 0, 0, 0);
      }
    }

    // ---- gated weights w[i=r][j=16g+4qq+m] (scale folded into garr) ----
    const bool diag = (jt == ntiles - 1);
    unsigned P[4][2];
#pragma unroll
    for (int g = 0; g < 4; ++g) {
      float wv[4];
#pragma unroll
      for (int m = 0; m < 4; ++m) {
        const int jl = 16 * g + 4 * qq + m;
        float ww = st[g][m] * __expf(g_sh[cur][jl] - gm_lane);
        if (diag && (j0 + jl > gr)) ww = 0.f;
        wv[m] = ww;
        den_p += ww;
      }
      P[g][0] = bfpair(wv[0], wv[1]);
      P[g][1] = bfpair(wv[2], wv[3]);
    }

    // ---- in-register exchange: C-layout -> A-fragments ----
    unsigned A0[4], A1[4];
#pragma unroll
    for (int m = 0; m < 4; ++m) {
      const int srcl = r + 16 * (2 * (qq & 1) + (m >> 1));
      const unsigned x0 = (unsigned)__shfl((int)P[0][m & 1], srcl);
      const unsigned x1 = (unsigned)__shfl((int)P[1][m & 1], srcl);
      const unsigned x2 = (unsigned)__shfl((int)P[2][m & 1], srcl);
      const unsigned x3 = (unsigned)__shfl((int)P[3][m & 1], srcl);
      A0[m] = (qq < 2) ? x0 : x1;
      A1[m] = (qq < 2) ? x2 : x3;
    }
    u32x4 ua0, ua1;
    ua0.x = A0[0]; ua0.y = A0[1]; ua0.z = A0[2]; ua0.w = A0[3];
    ua1.x = A1[0]; ua1.y = A1[1]; ua1.z = A1[2]; ua1.w = A1[3];
    const bf16x8 pa0 = __builtin_bit_cast(bf16x8, ua0);
    const bf16x8 pa1 = __builtin_bit_cast(bf16x8, ua1);

    // ---- PV: O[i][d] += w . V over two 32-j chunks ----
#pragma unroll
    for (int n = 0; n < 8; ++n) {
      const int d = 16 * n + r;
      const int u0 = (d * 8 + qq)     ^ (d & 7);
      const int u1 = (d * 8 + 4 + qq) ^ (d & 7);
      bf16x8 vb0 = *(const bf16x8*)&vbuf[cur][u0 * 16];
      bf16x8 vb1 = *(const bf16x8*)&vbuf[cur][u1 * 16];
      o[n] = __builtin_amdgcn_mfma_f32_16x16x32_bf16(pa0, vb0, o[n], 0, 0, 0);
      o[n] = __builtin_amdgcn_mfma_f32_16x16x32_bf16(pa1, vb1, o[n], 0, 0, 0);
    }
    __builtin_amdgcn_s_setprio(0);
    __syncthreads();
  }

  // ---- epilogue: normalizer + per-head LayerNorm + store ----
  float den_f = den_p;
  den_f += __shfl_xor(den_f, 16);
  den_f += __shfl_xor(den_f, 32);

  const float* wrow = wgt + h * DHEAD;
  float wv_n[8];
#pragma unroll
  for (int n = 0; n < 8; ++n) wv_n[n] = wrow[16 * n + r];

#pragma unroll
  for (int m = 0; m < 4; ++m) {
    const int iloc = 4 * qq + m;
    const float den_o = __shfl(den_f, iloc);
    const int grow = qb * 32 + 2 * iloc + w;
    const float csg = cs[bhS + grow];
    const float gmg = gmax[bhS + grow];
    const float norm = fmaxf(fabsf(den_o), __expf(-(csg + gmg))) + EPS_NORM;
    const float inv = 1.f / norm;
    float hv[8];
    float s1 = 0.f, s2 = 0.f;
#pragma unroll
    for (int n = 0; n < 8; ++n) {
      hv[n] = o[n][m] * inv;
      s1 += hv[n]; s2 += hv[n] * hv[n];
    }
    s1 += __shfl_xor(s1, 1); s1 += __shfl_xor(s1, 2);
    s1 += __shfl_xor(s1, 4); s1 += __shfl_xor(s1, 8);
    s2 += __shfl_xor(s2, 1); s2 += __shfl_xor(s2, 2);
    s2 += __shfl_xor(s2, 4); s2 += __shfl_xor(s2, 8);
    const float mu  = s1 * (1.f / 128.f);
    const float var = s2 * (1.f / 128.f) - mu * mu;
    const float rstd = rsqrtf(var + LN_EPS_C);
    float* orow = out + ((size_t)b * S_LEN + grow) * E_DIM + h * DHEAD;
#pragma unroll
    for (int n = 0; n < 8; ++n)
      orow[16 * n + r] = (hv[n] - mu) * rstd * wv_n[n];
  }
}

// ---------------- Kernel 3 (fallback, round-2 verified): fp32 staged in-loop ----------------
__global__ __launch_bounds__(256) void mlstm_mfma(
    const float* __restrict__ q, const float* __restrict__ k, const float* __restrict__ v,
    const float* __restrict__ cs, const float* __restrict__ garr, const float* __restrict__ gmax,
    const float* __restrict__ wgt, float* __restrict__ out) {
  __shared__ unsigned short k_lds[32][136];
  __shared__ unsigned int   vt_u32[128][20];
  __shared__ unsigned int   xch[4][16][20];
  __shared__ float          g_sh[32];

  const int bid = blockIdx.x;
  int qt;
  if (bid < 256) qt = 31 - (bid >> 4);
  else           qt = (bid - 256) >> 4;
  const int bh = bid & 15;
  const int b = bh >> 3, h = bh & 7;
  const int t = threadIdx.x;
  const int w = t >> 6;
  const int l = t & 63;
  const int r = l & 15;
  const int qq = l >> 4;
  const size_t bhS = (size_t)bh * S_LEN;

  const int gr = qt * 64 + 4 * r + w;
  const float gm_lane = gmax[bhS + gr];

  bf16x8 qfrag[4];
  {
    const float* qrow = q + ((size_t)b * S_LEN + gr) * E_DIM + h * DHEAD;
#pragma unroll
    for (int c = 0; c < 4; ++c) {
      const float4 f0 = *(const float4*)(qrow + 32 * c + 8 * qq);
      const float4 f1 = *(const float4*)(qrow + 32 * c + 8 * qq + 4);
      u32x4 u;
      u.x = bfpair(f0.x, f0.y); u.y = bfpair(f0.z, f0.w);
      u.z = bfpair(f1.x, f1.y); u.w = bfpair(f1.z, f1.w);
      qfrag[c] = __builtin_bit_cast(bf16x8, u);
    }
  }

  f32x4 o[8];
#pragma unroll
  for (int n = 0; n < 8; ++n) o[n] = (f32x4){0.f, 0.f, 0.f, 0.f};
  float den_p = 0.f;

  const int kj = t >> 3, ks = t & 7;
  const int vjp = t & 15, vds = t >> 4;

  const int ntiles = 2 * qt + 2;
  for (int jt = 0; jt < ntiles; ++jt) {
    const int j0 = jt * 32;
    {
      const float* src = k + ((size_t)b * S_LEN + j0 + kj) * E_DIM + h * DHEAD + ks * 16;
      float4 f0 = *(const float4*)(src);
      float4 f1 = *(const float4*)(src + 4);
      float4 f2 = *(const float4*)(src + 8);
      float4 f3 = *(const float4*)(src + 12);
      u32x4 ua, ub;
      ua.x = bfpair(f0.x, f0.y); ua.y = bfpair(f0.z, f0.w);
      ua.z = bfpair(f1.x, f1.y); ua.w = bfpair(f1.z, f1.w);
      ub.x = bfpair(f2.x, f2.y); ub.y = bfpair(f2.z, f2.w);
      ub.z = bfpair(f3.x, f3.y); ub.w = bfpair(f3.z, f3.w);
      *(u32x4*)&k_lds[kj][ks * 16]     = ua;
      *(u32x4*)&k_lds[kj][ks * 16 + 8] = ub;
    }
    {
      const float* s0 = v + ((size_t)b * S_LEN + j0 + 2 * vjp) * E_DIM + h * DHEAD + vds * 8;
      const float* s1 = s0 + E_DIM;
      float4 a0 = *(const float4*)(s0);
      float4 a1 = *(const float4*)(s0 + 4);
      float4 b0 = *(const float4*)(s1);
      float4 b1 = *(const float4*)(s1 + 4);
      vt_u32[vds * 8 + 0][vjp] = bfpair(a0.x, b0.x);
      vt_u32[vds * 8 + 1][vjp] = bfpair(a0.y, b0.y);
      vt_u32[vds * 8 + 2][vjp] = bfpair(a0.z, b0.z);
      vt_u32[vds * 8 + 3][vjp] = bfpair(a0.w, b0.w);
      vt_u32[vds * 8 + 4][vjp] = bfpair(a1.x, b1.x);
      vt_u32[vds * 8 + 5][vjp] = bfpair(a1.y, b1.y);
      vt_u32[vds * 8 + 6][vjp] = bfpair(a1.z, b1.z);
      vt_u32[vds * 8 + 7][vjp] = bfpair(a1.w, b1.w);
    }
    if (t < 32) g_sh[t] = garr[bhS + j0 + t];
    __syncthreads();

    f32x4 st0 = {0, 0, 0, 0}, st1 = {0, 0, 0, 0};
#pragma unroll
    for (int c = 0; c < 4; ++c) {
      bf16x8 ka0 = *(const bf16x8*)&k_lds[r][32 * c + 8 * qq];
      bf16x8 ka1 = *(const bf16x8*)&k_lds[16 + r][32 * c + 8 * qq];
      st0 = __builtin_amdgcn_mfma_f32_16x16x32_bf16(ka0, qfrag[c], st0, 0, 0, 0);
      st1 = __builtin_amdgcn_mfma_f32_16x16x32_bf16(ka1, qfrag[c], st1, 0, 0, 0);
    }

    const bool diag = (jt >= 2 * qt);
    float wv0[4], wv1[4];
#pragma unroll
    for (int reg = 0; reg < 4; ++reg) {
      const int jl0 = 4 * qq + reg, jl1 = 16 + 4 * qq + reg;
      const float e0 = __expf(g_sh[jl0] - gm_lane);
      const float e1 = __expf(g_sh[jl1] - gm_lane);
      float w0 = st0[reg] * RSQ_DH * e0;
      float w1 = st1[reg] * RSQ_DH * e1;
      if (diag) {
        if (j0 + jl0 > gr) w0 = 0.f;
        if (j0 + jl1 > gr) w1 = 0.f;
      }
      wv0[reg] = w0; wv1[reg] = w1;
      den_p += w0 + w1;
    }

    u32x2 p0, p1;
    p0.x = bfpair(wv0[0], wv0[1]); p0.y = bfpair(wv0[2], wv0[3]);
    p1.x = bfpair(wv1[0], wv1[1]); p1.y = bfpair(wv1[2], wv1[3]);
    *(u32x2*)&xch[w][r][2 * qq]     = p0;
    *(u32x2*)&xch[w][r][8 + 2 * qq] = p1;
    __builtin_amdgcn_wave_barrier();
    bf16x8 pa = *(const bf16x8*)&xch[w][r][4 * qq];
    __builtin_amdgcn_wave_barrier();

#pragma unroll
    for (int n = 0; n < 8; ++n) {
      bf16x8 vb = *(const bf16x8*)&vt_u32[16 * n + r][4 * qq];
      o[n] = __builtin_amdgcn_mfma_f32_16x16x32_bf16(pa, vb, o[n], 0, 0, 0);
    }
    __syncthreads();
  }

  float den_f = den_p;
  den_f += __shfl_xor(den_f, 16);
  den_f += __shfl_xor(den_f, 32);

  const float* wrow = wgt + h * DHEAD;
  float wv_n[8];
#pragma unroll
  for (int n = 0; n < 8; ++n) wv_n[n] = wrow[16 * n + r];

#pragma unroll
  for (int reg = 0; reg < 4; ++reg) {
    const int iloc = 4 * qq + reg;
    const float den_o = __shfl(den_f, iloc);
    const int grow = qt * 64 + 4 * iloc + w;
    const float csg = cs[bhS + grow];
    const float gmg = gmax[bhS + grow];
    const float norm = fmaxf(fabsf(den_o), __expf(-(csg + gmg))) + EPS_NORM;
    const float inv = 1.f / norm;
    float hv[8];
    float s1 = 0.f, s2 = 0.f;
#pragma unroll
    for (int n = 0; n < 8; ++n) {
      hv[n] = o[n][reg] * inv;
      s1 += hv[n]; s2 += hv[n] * hv[n];
    }
    s1 += __shfl_xor(s1, 1); s1 += __shfl_xor(s1, 2);
    s1 += __shfl_xor(s1, 4); s1 += __shfl_xor(s1, 8);
    s2 += __shfl_xor(s2, 1); s2 += __shfl_xor(s2, 2);
    s2 += __shfl_xor(s2, 4); s2 += __shfl_xor(s2, 8);
    const float mu  = s1 * (1.f / 128.f);
    const float var = s2 * (1.f / 128.f) - mu * mu;
    const float rstd = rsqrtf(var + LN_EPS_C);
    float* orow = out + ((size_t)b * S_LEN + grow) * E_DIM + h * DHEAD;
#pragma unroll
    for (int n = 0; n < 8; ++n)
      orow[16 * n + r] = (hv[n] - mu) * rstd * wv_n[n];
  }
}

extern "C" void kernel_launch(void* const* d_in, const int* in_sizes, int n_in,
                              void* d_out, int out_size, void* d_ws, size_t ws_size,
                              hipStream_t stream) {
  (void)in_sizes; (void)n_in; (void)out_size;
  const float* q   = (const float*)d_in[0];
  const float* k   = (const float*)d_in[1];
  const float* v   = (const float*)d_in[2];
  const float* Wi  = (const float*)d_in[3];
  const float* bi  = (const float*)d_in[4];
  const float* Wf  = (const float*)d_in[5];
  const float* bf  = (const float*)d_in[6];
  const float* wgt = (const float*)d_in[7];
  float* out = (float*)d_out;
  float* ws  = (float*)d_ws;
  const int BNS = 2 * NHEAD * S_LEN;              // 32768
  float* ig_pre = ws;
  float* fg_pre = ws + (size_t)BNS;
  float* cs     = ws + (size_t)2 * BNS;
  float* gv     = ws + (size_t)3 * BNS;
  float* gmaxs  = ws + (size_t)4 * BNS;
  unsigned short* kb  = (unsigned short*)(ws + (size_t)5 * BNS);
  unsigned short* vtb = kb + (size_t)16 * S_LEN * DHEAD;

  const size_t need = (size_t)5 * BNS * 4 + (size_t)2 * 16 * S_LEN * DHEAD * 2;

  if (ws_size >= need) {
    gates_fused<<<512, 256, 0, stream>>>(q, k, v, Wi, bi, Wf, bf, ig_pre, fg_pre, kb);
    vtrans<<<512, 256, 0, stream>>>(v, vtb);
    scan_kernel<<<16, 256, 0, stream>>>(ig_pre, fg_pre, cs, gv, gmaxs, LNRSQ);
    mlstm_mfma3<<<1024, 128, 0, stream>>>(kb, vtb, q, cs, gv, gmaxs, wgt, out);
  } else {
    gates_fused<<<512, 256, 0, stream>>>(q, k, v, Wi, bi, Wf, bf, ig_pre, fg_pre, nullptr);
    scan_kernel<<<16, 256, 0, stream>>>(ig_pre, fg_pre, cs, gv, gmaxs, 0.0f);
    mlstm_mfma<<<512, 256, 0, stream>>>(q, k, v, cs, gv, gmaxs, wgt, out);
  }
}

// Round 7
// 111.282 us; speedup vs baseline: 8.9445x; 1.0502x over previous
//
#include <hip/hip_runtime.h>
#include <math.h>

#define S_LEN 2048
#define E_DIM 1024
#define NHEAD 8
#define DHEAD 128

typedef short bf16x8 __attribute__((ext_vector_type(8)));
typedef float f32x4 __attribute__((ext_vector_type(4)));
typedef unsigned int u32x4 __attribute__((ext_vector_type(4)));
typedef unsigned int u32x2 __attribute__((ext_vector_type(2)));

constexpr float RSQ_DH  = 0.08838834764831843f; // 1/sqrt(128)
constexpr float LNRSQ   = -2.4260151319598084f; // ln(1/sqrt(128))
constexpr float EPS_NORM = 1e-6f;
constexpr float LN_EPS_C = 1e-6f;

__device__ inline unsigned bfpair(float lo, float hi) {
  unsigned a = __builtin_bit_cast(unsigned, lo);
  unsigned b = __builtin_bit_cast(unsigned, hi);
  a = (a + 0x7fffu + ((a >> 16) & 1u)) >> 16;
  b = (b + 0x7fffu + ((b >> 16) & 1u)) >> 16;
  return a | (b << 16);
}

__device__ inline unsigned cvtpk(float lo, float hi) {
  unsigned r;
  asm("v_cvt_pk_bf16_f32 %0, %1, %2" : "=v"(r) : "v"(lo), "v"(hi));
  return r;
}

__device__ inline void gload_lds16(const void* g, void* lds) {
  __builtin_amdgcn_global_load_lds(
      (const __attribute__((address_space(1))) unsigned int*)g,
      (__attribute__((address_space(3))) unsigned int*)lds, 16, 0, 0);
}
__device__ inline void gload_lds4(const void* g, void* lds) {
  __builtin_amdgcn_global_load_lds(
      (const __attribute__((address_space(1))) unsigned int*)g,
      (__attribute__((address_space(3))) unsigned int*)lds, 4, 0, 0);
}

// ---------------- Kernel 1: gates (8 rows/block) + bf16 K copy ----------------
__global__ __launch_bounds__(256) void gates_fused(
    const float* __restrict__ q, const float* __restrict__ k, const float* __restrict__ v,
    const float* __restrict__ Wi, const float* __restrict__ bi,
    const float* __restrict__ Wf, const float* __restrict__ bf,
    float* __restrict__ ig_pre, float* __restrict__ fg_pre,
    unsigned short* __restrict__ kb) {
  const int t = threadIdx.x;
  const int row0 = blockIdx.x * 8;
  const int b = row0 >> 11;
  const int s0 = row0 & 2047;
  float p[8][16];
#pragma unroll
  for (int rr = 0; rr < 8; ++rr)
#pragma unroll
    for (int c = 0; c < 16; ++c) p[rr][c] = 0.f;

#pragma unroll
  for (int i = 0; i < 3; ++i) {
    const float* base = (i == 0) ? q : (i == 1) ? k : v;
    float xs[8][4];
#pragma unroll
    for (int rr = 0; rr < 8; ++rr) {
      const float4 xv = *(const float4*)(base + (size_t)(row0 + rr) * E_DIM + t * 4);
      xs[rr][0] = xv.x; xs[rr][1] = xv.y; xs[rr][2] = xv.z; xs[rr][3] = xv.w;
    }
#pragma unroll
    for (int j = 0; j < 4; ++j) {
      const int ge = i * E_DIM + t * 4 + j;
      const float4 wiA = *(const float4*)(Wi + (size_t)ge * 8);
      const float4 wiB = *(const float4*)(Wi + (size_t)ge * 8 + 4);
      const float4 wfA = *(const float4*)(Wf + (size_t)ge * 8);
      const float4 wfB = *(const float4*)(Wf + (size_t)ge * 8 + 4);
      const float wv16[16] = {wiA.x, wiA.y, wiA.z, wiA.w, wiB.x, wiB.y, wiB.z, wiB.w,
                              wfA.x, wfA.y, wfA.z, wfA.w, wfB.x, wfB.y, wfB.z, wfB.w};
#pragma unroll
      for (int rr = 0; rr < 8; ++rr) {
        const float x = xs[rr][j];
#pragma unroll
        for (int c = 0; c < 16; ++c) p[rr][c] += x * wv16[c];
      }
    }
    if (i == 1 && kb != nullptr) {
      const int h = (t * 4) >> 7, d = (t * 4) & 127;
#pragma unroll
      for (int rr = 0; rr < 8; ++rr) {
        u32x2 pk;
        pk.x = bfpair(xs[rr][0], xs[rr][1]);
        pk.y = bfpair(xs[rr][2], xs[rr][3]);
        *(u32x2*)(kb + (((size_t)b * NHEAD + h) * S_LEN + (s0 + rr)) * DHEAD + d) = pk;
      }
    }
  }

#pragma unroll
  for (int rr = 0; rr < 8; ++rr)
#pragma unroll
    for (int c = 0; c < 16; ++c) {
      float val = p[rr][c];
      val += __shfl_xor(val, 1);
      val += __shfl_xor(val, 2);
      val += __shfl_xor(val, 4);
      val += __shfl_xor(val, 8);
      val += __shfl_xor(val, 16);
      val += __shfl_xor(val, 32);
      p[rr][c] = val;
    }
  __shared__ float sred[4][8][16];
  const int wid = t >> 6, lane = t & 63;
  if (lane == 0) {
#pragma unroll
    for (int rr = 0; rr < 8; ++rr)
#pragma unroll
      for (int c = 0; c < 16; ++c) sred[wid][rr][c] = p[rr][c];
  }
  __syncthreads();
  if (t < 128) {
    const int rr = t >> 4, c = t & 15;
    float sum = sred[0][rr][c] + sred[1][rr][c] + sred[2][rr][c] + sred[3][rr][c];
    const int h = c & 7;
    const int row = row0 + rr;
    const int bb = row / S_LEN, s = row % S_LEN;
    if (c < 8) ig_pre[((size_t)bb * NHEAD + h) * S_LEN + s] = sum + bi[h];
    else       fg_pre[((size_t)bb * NHEAD + h) * S_LEN + s] = sum + bf[h];
  }
}

// ---------------- Kernel 1b: V transpose to bf16 (bh, d, s) ----------------
__global__ __launch_bounds__(256) void vtrans(const float* __restrict__ v,
                                              unsigned short* __restrict__ vtb) {
  __shared__ unsigned int tile[128][36];
  const int bid = blockIdx.x;
  const int bh = bid >> 5, st = bid & 31;
  const int b = bh >> 3, h = bh & 7;
  const int s0 = st * 64;
  const int t = threadIdx.x;
#pragma unroll
  for (int i = 0; i < 4; ++i) {
    const int task = t + 256 * i;
    const int sp = task & 31, dq = task >> 5;
    const float* src = v + ((size_t)b * S_LEN + s0 + 2 * sp) * E_DIM + h * DHEAD + dq * 4;
    const float4 r0 = *(const float4*)(src);
    const float4 r1 = *(const float4*)(src + E_DIM);
    tile[dq * 4 + 0][sp] = bfpair(r0.x, r1.x);
    tile[dq * 4 + 1][sp] = bfpair(r0.y, r1.y);
    tile[dq * 4 + 2][sp] = bfpair(r0.z, r1.z);
    tile[dq * 4 + 3][sp] = bfpair(r0.w, r1.w);
  }
  __syncthreads();
#pragma unroll
  for (int i = 0; i < 2; ++i) {
    const int task = t + 256 * i;
    const int d = task >> 2, c4 = task & 3;
    u32x4 w0, w1;
    w0.x = tile[d][c4 * 8 + 0]; w0.y = tile[d][c4 * 8 + 1];
    w0.z = tile[d][c4 * 8 + 2]; w0.w = tile[d][c4 * 8 + 3];
    w1.x = tile[d][c4 * 8 + 4]; w1.y = tile[d][c4 * 8 + 5];
    w1.z = tile[d][c4 * 8 + 6]; w1.w = tile[d][c4 * 8 + 7];
    unsigned short* dst = vtb + ((size_t)bh * DHEAD + d) * S_LEN + s0 + c4 * 16;
    *(u32x4*)(dst)     = w0;
    *(u32x4*)(dst + 8) = w1;
  }
}

// ---------------- Kernel 2: log-sigmoid + cumsum + prefix-max ----------------
__global__ __launch_bounds__(256) void scan_kernel(
    const float* __restrict__ ig_pre, const float* __restrict__ fg_pre,
    float* __restrict__ cs_out, float* __restrict__ g_out, float* __restrict__ gmax_out,
    float g_add) {
  const int bhh = blockIdx.x;
  const int t = threadIdx.x;
  const size_t base = (size_t)bhh * S_LEN;
  float vals[8];
  float run = 0.f;
#pragma unroll
  for (int i = 0; i < 8; ++i) {
    const float x = fg_pre[base + t * 8 + i];
    const float lf = fminf(x, 0.f) - log1pf(__expf(-fabsf(x)));
    run += lf;
    vals[i] = run;
  }
  __shared__ float sums[256];
  sums[t] = run;
  __syncthreads();
  for (int off = 1; off < 256; off <<= 1) {
    const float other = (t >= off) ? sums[t - off] : 0.f;
    __syncthreads();
    sums[t] += other;
    __syncthreads();
  }
  const float prefix = (t > 0) ? sums[t - 1] : 0.f;
  float g_loc[8], gm_loc[8];
  float lmax = -3.4e38f;
#pragma unroll
  for (int i = 0; i < 8; ++i) {
    const float csv = vals[i] + prefix;
    vals[i] = csv;
    const float gg = ig_pre[base + t * 8 + i] - csv;
    g_loc[i] = gg;
    lmax = fmaxf(lmax, gg);
    gm_loc[i] = lmax;
  }
  __shared__ float maxs[256];
  maxs[t] = lmax;
  __syncthreads();
  for (int off = 1; off < 256; off <<= 1) {
    const float other = (t >= off) ? maxs[t - off] : -3.4e38f;
    __syncthreads();
    maxs[t] = fmaxf(maxs[t], other);
    __syncthreads();
  }
  const float pmax = (t > 0) ? maxs[t - 1] : -3.4e38f;
#pragma unroll
  for (int i = 0; i < 8; ++i) {
    cs_out[base + t * 8 + i]   = vals[i];
    g_out[base + t * 8 + i]    = g_loc[i] + g_add;
    gmax_out[base + t * 8 + i] = fmaxf(gm_loc[i], pmax);
  }
}

// ---------------- Kernel 3 (fast): 4-wave blocks, dbuf + counted vmcnt ----------------
// Block: (bh, qb), 64 q-rows, 4 waves. Per stage: 9 vmem ops/wave (4 K + 4 V + 1 g).
__global__ __launch_bounds__(256) void mlstm_mfma4(
    const unsigned short* __restrict__ kb, const unsigned short* __restrict__ vtb,
    const float* __restrict__ q,
    const float* __restrict__ cs, const float* __restrict__ garr, const float* __restrict__ gmax,
    const float* __restrict__ wgt, float* __restrict__ out) {
  __shared__ __align__(16) unsigned char kbuf[2][16384];  // K tile 64x128 bf16 (swizzled)
  __shared__ __align__(16) unsigned char vbuf[2][16384];  // V^T tile 128x64 bf16 (swizzled)
  __shared__ float g_sh[2][64];

  const int bid = blockIdx.x;
  int qb;
  if (bid < 256) qb = 31 - (bid >> 4);      // heavy-first; CU pairs qb with 31-qb
  else           qb = (bid - 256) >> 4;
  const int g16 = bid & 15;
  const int bh = 2 * (g16 & 7) + (g16 >> 3);   // same-bh blocks on same XCD
  const int b = bh >> 3, h = bh & 7;
  const int t = threadIdx.x;
  const int w = t >> 6;        // 0..3
  const int l = t & 63;
  const int r = l & 15;
  const int qq = l >> 4;
  const size_t bhS = (size_t)bh * S_LEN;

  const int gr = qb * 64 + 4 * r + w;          // lane's q-row
  const float gm_lane = gmax[bhS + gr];

  // Q fragment (B-operand): qfrag[c] = Q[i=r][d = 32c + 8qq + e]
  bf16x8 qfrag[4];
  {
    const float* qrow = q + ((size_t)b * S_LEN + gr) * E_DIM + h * DHEAD;
#pragma unroll
    for (int c = 0; c < 4; ++c) {
      const float4 f0 = *(const float4*)(qrow + 32 * c + 8 * qq);
      const float4 f1 = *(const float4*)(qrow + 32 * c + 8 * qq + 4);
      u32x4 u;
      u.x = bfpair(f0.x, f0.y); u.y = bfpair(f0.z, f0.w);
      u.z = bfpair(f1.x, f1.y); u.w = bfpair(f1.z, f1.w);
      qfrag[c] = __builtin_bit_cast(bf16x8, u);
    }
  }

  f32x4 o[8];
#pragma unroll
  for (int n = 0; n < 8; ++n) o[n] = (f32x4){0.f, 0.f, 0.f, 0.f};
  float den_p = 0.f;

  const unsigned short* kt = kb + bhS * DHEAD;
  const unsigned short* vt = vtb + (size_t)bh * DHEAD * S_LEN;

  const int ntiles = qb + 1;

  // ---- stage tile jt_ into buffer bufi: exactly 9 vmem ops per wave ----
  auto stage = [&](int jt_, int bufi) {
    const int j0 = jt_ * 64;
#pragma unroll
    for (int a = 0; a < 4; ++a) {
      const int m = w * 256 + a * 64 + l;       // physical 16B unit
      const int u = m ^ ((m >> 4) & 7);         // logical unit (involution)
      const int j = u >> 4, seg = u & 15;
      gload_lds16(kt + ((size_t)(j0 + j)) * DHEAD + seg * 8,
                  &kbuf[bufi][(w * 256 + a * 64) * 16]);
    }
#pragma unroll
    for (int a = 0; a < 4; ++a) {
      const int m = w * 256 + a * 64 + l;
      const int u = m ^ ((m >> 3) & 7);
      const int d = u >> 3, qv = u & 7;
      gload_lds16(vt + (size_t)d * S_LEN + j0 + qv * 8,
                  &vbuf[bufi][(w * 256 + a * 64) * 16]);
    }
    // g tile: PER-LANE global source (lane l -> g[j0+l]), uniform LDS base.
    gload_lds4(garr + bhS + j0 + l, &g_sh[bufi][0]);
  };

  // ---- per-tile compute; cur/diag become literals at every call site ----
  auto body = [&](int jt_, int cur, bool diag) {
    const int j0 = jt_ * 64;
    __builtin_amdgcn_s_setprio(1);
    // S^T: st[g] = K[16g..16g+15] . Q, over 4 d-chunks
    f32x4 st[4];
#pragma unroll
    for (int g = 0; g < 4; ++g) st[g] = (f32x4){0.f, 0.f, 0.f, 0.f};
#pragma unroll
    for (int c = 0; c < 4; ++c) {
#pragma unroll
      for (int g = 0; g < 4; ++g) {
        const int u = ((16 * g + r) * 16 + 4 * c + qq) ^ (r & 7);
        bf16x8 ka = *(const bf16x8*)&kbuf[cur][u * 16];
        st[g] = __builtin_amdgcn_mfma_f32_16x16x32_bf16(ka, qfrag[c], st[g], 0, 0, 0);
      }
    }
    __builtin_amdgcn_s_setprio(0);

    // gated weights w[i=r][j=16g+4qq+m] (1/sqrt(DH) folded into garr)
    unsigned P[4][2];
#pragma unroll
    for (int g = 0; g < 4; ++g) {
      float wv[4];
#pragma unroll
      for (int m = 0; m < 4; ++m) {
        const int jl = 16 * g + 4 * qq + m;
        float ww = st[g][m] * __expf(g_sh[cur][jl] - gm_lane);
        if (diag && (j0 + jl > gr)) ww = 0.f;
        wv[m] = ww;
        den_p += ww;
      }
      P[g][0] = cvtpk(wv[0], wv[1]);
      P[g][1] = cvtpk(wv[2], wv[3]);
    }

    // in-register exchange: C-layout -> A-fragments (j 0..31 and 32..63)
    unsigned A0[4], A1[4];
#pragma unroll
    for (int m = 0; m < 4; ++m) {
      const int srcl = r + 16 * (2 * (qq & 1) + (m >> 1));
      const unsigned x0 = (unsigned)__shfl((int)P[0][m & 1], srcl);
      const unsigned x1 = (unsigned)__shfl((int)P[1][m & 1], srcl);
      const unsigned x2 = (unsigned)__shfl((int)P[2][m & 1], srcl);
      const unsigned x3 = (unsigned)__shfl((int)P[3][m & 1], srcl);
      A0[m] = (qq < 2) ? x0 : x1;
      A1[m] = (qq < 2) ? x2 : x3;
    }
    u32x4 ua0, ua1;
    ua0.x = A0[0]; ua0.y = A0[1]; ua0.z = A0[2]; ua0.w = A0[3];
    ua1.x = A1[0]; ua1.y = A1[1]; ua1.z = A1[2]; ua1.w = A1[3];
    const bf16x8 pa0 = __builtin_bit_cast(bf16x8, ua0);
    const bf16x8 pa1 = __builtin_bit_cast(bf16x8, ua1);

    // PV: O[i][d] += w . V over two 32-j chunks
    __builtin_amdgcn_s_setprio(1);
#pragma unroll
    for (int n = 0; n < 8; ++n) {
      const int d = 16 * n + r;
      const int u0 = (d * 8 + qq)     ^ (d & 7);
      const int u1 = (d * 8 + 4 + qq) ^ (d & 7);
      bf16x8 vb0 = *(const bf16x8*)&vbuf[cur][u0 * 16];
      bf16x8 vb1 = *(const bf16x8*)&vbuf[cur][u1 * 16];
      o[n] = __builtin_amdgcn_mfma_f32_16x16x32_bf16(pa0, vb0, o[n], 0, 0, 0);
      o[n] = __builtin_amdgcn_mfma_f32_16x16x32_bf16(pa1, vb1, o[n], 0, 0, 0);
    }
    __builtin_amdgcn_s_setprio(0);
  };

  stage(0, 0);
  const int M = ntiles - 1;    // index of the diagonal tile
  int jt = 0;
  for (; jt + 2 <= M; jt += 2) {
    stage(jt + 1, 1);
    asm volatile("s_waitcnt vmcnt(9)" ::: "memory");
    __builtin_amdgcn_sched_barrier(0);
    __syncthreads();
    body(jt, 0, false);
    __syncthreads();
    stage(jt + 2, 0);
    asm volatile("s_waitcnt vmcnt(9)" ::: "memory");
    __builtin_amdgcn_sched_barrier(0);
    __syncthreads();
    body(jt + 1, 1, false);
    __syncthreads();
  }
  if (jt == M - 1) {           // one non-diag tile left, then diag (odd M)
    stage(M, 1);
    asm volatile("s_waitcnt vmcnt(9)" ::: "memory");
    __builtin_amdgcn_sched_barrier(0);
    __syncthreads();
    body(jt, 0, false);
    __syncthreads();
    asm volatile("s_waitcnt vmcnt(0)" ::: "memory");
    __builtin_amdgcn_sched_barrier(0);
    __syncthreads();
    body(M, 1, true);
  } else {                     // jt == M: diag tile only (even M), already staged in buf0
    asm volatile("s_waitcnt vmcnt(0)" ::: "memory");
    __builtin_amdgcn_sched_barrier(0);
    __syncthreads();
    body(M, 0, true);
  }

  // ---- epilogue: normalizer + per-head LayerNorm + store ----
  float den_f = den_p;
  den_f += __shfl_xor(den_f, 16);
  den_f += __shfl_xor(den_f, 32);

  const float* wrow = wgt + h * DHEAD;
  float wv_n[8];
#pragma unroll
  for (int n = 0; n < 8; ++n) wv_n[n] = wrow[16 * n + r];

#pragma unroll
  for (int m = 0; m < 4; ++m) {
    const int iloc = 4 * qq + m;
    const float den_o = __shfl(den_f, iloc);
    const int grow = qb * 64 + 4 * iloc + w;
    const float csg = cs[bhS + grow];
    const float gmg = gmax[bhS + grow];
    const float norm = fmaxf(fabsf(den_o), __expf(-(csg + gmg))) + EPS_NORM;
    const float inv = 1.f / norm;
    float hv[8];
    float s1 = 0.f, s2 = 0.f;
#pragma unroll
    for (int n = 0; n < 8; ++n) {
      hv[n] = o[n][m] * inv;
      s1 += hv[n]; s2 += hv[n] * hv[n];
    }
    s1 += __shfl_xor(s1, 1); s1 += __shfl_xor(s1, 2);
    s1 += __shfl_xor(s1, 4); s1 += __shfl_xor(s1, 8);
    s2 += __shfl_xor(s2, 1); s2 += __shfl_xor(s2, 2);
    s2 += __shfl_xor(s2, 4); s2 += __shfl_xor(s2, 8);
    const float mu  = s1 * (1.f / 128.f);
    const float var = s2 * (1.f / 128.f) - mu * mu;
    const float rstd = rsqrtf(var + LN_EPS_C);
    float* orow = out + ((size_t)b * S_LEN + grow) * E_DIM + h * DHEAD;
#pragma unroll
    for (int n = 0; n < 8; ++n)
      orow[16 * n + r] = (hv[n] - mu) * rstd * wv_n[n];
  }
}

// ---------------- Kernel 3 (fallback, round-2 verified): fp32 staged in-loop ----------------
__global__ __launch_bounds__(256) void mlstm_mfma(
    const float* __restrict__ q, const float* __restrict__ k, const float* __restrict__ v,
    const float* __restrict__ cs, const float* __restrict__ garr, const float* __restrict__ gmax,
    const float* __restrict__ wgt, float* __restrict__ out) {
  __shared__ unsigned short k_lds[32][136];
  __shared__ unsigned int   vt_u32[128][20];
  __shared__ unsigned int   xch[4][16][20];
  __shared__ float          g_sh[32];

  const int bid = blockIdx.x;
  int qt;
  if (bid < 256) qt = 31 - (bid >> 4);
  else           qt = (bid - 256) >> 4;
  const int bh = bid & 15;
  const int b = bh >> 3, h = bh & 7;
  const int t = threadIdx.x;
  const int w = t >> 6;
  const int l = t & 63;
  const int r = l & 15;
  const int qq = l >> 4;
  const size_t bhS = (size_t)bh * S_LEN;

  const int gr = qt * 64 + 4 * r + w;
  const float gm_lane = gmax[bhS + gr];

  bf16x8 qfrag[4];
  {
    const float* qrow = q + ((size_t)b * S_LEN + gr) * E_DIM + h * DHEAD;
#pragma unroll
    for (int c = 0; c < 4; ++c) {
      const float4 f0 = *(const float4*)(qrow + 32 * c + 8 * qq);
      const float4 f1 = *(const float4*)(qrow + 32 * c + 8 * qq + 4);
      u32x4 u;
      u.x = bfpair(f0.x, f0.y); u.y = bfpair(f0.z, f0.w);
      u.z = bfpair(f1.x, f1.y); u.w = bfpair(f1.z, f1.w);
      qfrag[c] = __builtin_bit_cast(bf16x8, u);
    }
  }

  f32x4 o[8];
#pragma unroll
  for (int n = 0; n < 8; ++n) o[n] = (f32x4){0.f, 0.f, 0.f, 0.f};
  float den_p = 0.f;

  const int kj = t >> 3, ks = t & 7;
  const int vjp = t & 15, vds = t >> 4;

  const int ntiles = 2 * qt + 2;
  for (int jt = 0; jt < ntiles; ++jt) {
    const int j0 = jt * 32;
    {
      const float* src = k + ((size_t)b * S_LEN + j0 + kj) * E_DIM + h * DHEAD + ks * 16;
      float4 f0 = *(const float4*)(src);
      float4 f1 = *(const float4*)(src + 4);
      float4 f2 = *(const float4*)(src + 8);
      float4 f3 = *(const float4*)(src + 12);
      u32x4 ua, ub;
      ua.x = bfpair(f0.x, f0.y); ua.y = bfpair(f0.z, f0.w);
      ua.z = bfpair(f1.x, f1.y); ua.w = bfpair(f1.z, f1.w);
      ub.x = bfpair(f2.x, f2.y); ub.y = bfpair(f2.z, f2.w);
      ub.z = bfpair(f3.x, f3.y); ub.w = bfpair(f3.z, f3.w);
      *(u32x4*)&k_lds[kj][ks * 16]     = ua;
      *(u32x4*)&k_lds[kj][ks * 16 + 8] = ub;
    }
    {
      const float* s0 = v + ((size_t)b * S_LEN + j0 + 2 * vjp) * E_DIM + h * DHEAD + vds * 8;
      const float* s1 = s0 + E_DIM;
      float4 a0 = *(const float4*)(s0);
      float4 a1 = *(const float4*)(s0 + 4);
      float4 b0 = *(const float4*)(s1);
      float4 b1 = *(const float4*)(s1 + 4);
      vt_u32[vds * 8 + 0][vjp] = bfpair(a0.x, b0.x);
      vt_u32[vds * 8 + 1][vjp] = bfpair(a0.y, b0.y);
      vt_u32[vds * 8 + 2][vjp] = bfpair(a0.z, b0.z);
      vt_u32[vds * 8 + 3][vjp] = bfpair(a0.w, b0.w);
      vt_u32[vds * 8 + 4][vjp] = bfpair(a1.x, b1.x);
      vt_u32[vds * 8 + 5][vjp] = bfpair(a1.y, b1.y);
      vt_u32[vds * 8 + 6][vjp] = bfpair(a1.z, b1.z);
      vt_u32[vds * 8 + 7][vjp] = bfpair(a1.w, b1.w);
    }
    if (t < 32) g_sh[t] = garr[bhS + j0 + t];
    __syncthreads();

    f32x4 st0 = {0, 0, 0, 0}, st1 = {0, 0, 0, 0};
#pragma unroll
    for (int c = 0; c < 4; ++c) {
      bf16x8 ka0 = *(const bf16x8*)&k_lds[r][32 * c + 8 * qq];
      bf16x8 ka1 = *(const bf16x8*)&k_lds[16 + r][32 * c + 8 * qq];
      st0 = __builtin_amdgcn_mfma_f32_16x16x32_bf16(ka0, qfrag[c], st0, 0, 0, 0);
      st1 = __builtin_amdgcn_mfma_f32_16x16x32_bf16(ka1, qfrag[c], st1, 0, 0, 0);
    }

    const bool diag = (jt >= 2 * qt);
    float wv0[4], wv1[4];
#pragma unroll
    for (int reg = 0; reg < 4; ++reg) {
      const int jl0 = 4 * qq + reg, jl1 = 16 + 4 * qq + reg;
      const float e0 = __expf(g_sh[jl0] - gm_lane);
      const float e1 = __expf(g_sh[jl1] - gm_lane);
      float w0 = st0[reg] * RSQ_DH * e0;
      float w1 = st1[reg] * RSQ_DH * e1;
      if (diag) {
        if (j0 + jl0 > gr) w0 = 0.f;
        if (j0 + jl1 > gr) w1 = 0.f;
      }
      wv0[reg] = w0; wv1[reg] = w1;
      den_p += w0 + w1;
    }

    u32x2 p0, p1;
    p0.x = bfpair(wv0[0], wv0[1]); p0.y = bfpair(wv0[2], wv0[3]);
    p1.x = bfpair(wv1[0], wv1[1]); p1.y = bfpair(wv1[2], wv1[3]);
    *(u32x2*)&xch[w][r][2 * qq]     = p0;
    *(u32x2*)&xch[w][r][8 + 2 * qq] = p1;
    __builtin_amdgcn_wave_barrier();
    bf16x8 pa = *(const bf16x8*)&xch[w][r][4 * qq];
    __builtin_amdgcn_wave_barrier();

#pragma unroll
    for (int n = 0; n < 8; ++n) {
      bf16x8 vb = *(const bf16x8*)&vt_u32[16 * n + r][4 * qq];
      o[n] = __builtin_amdgcn_mfma_f32_16x16x32_bf16(pa, vb, o[n], 0, 0, 0);
    }
    __syncthreads();
  }

  float den_f = den_p;
  den_f += __shfl_xor(den_f, 16);
  den_f += __shfl_xor(den_f, 32);

  const float* wrow = wgt + h * DHEAD;
  float wv_n[8];
#pragma unroll
  for (int n = 0; n < 8; ++n) wv_n[n] = wrow[16 * n + r];

#pragma unroll
  for (int reg = 0; reg < 4; ++reg) {
    const int iloc = 4 * qq + reg;
    const float den_o = __shfl(den_f, iloc);
    const int grow = qt * 64 + 4 * iloc + w;
    const float csg = cs[bhS + grow];
    const float gmg = gmax[bhS + grow];
    const float norm = fmaxf(fabsf(den_o), __expf(-(csg + gmg))) + EPS_NORM;
    const float inv = 1.f / norm;
    float hv[8];
    float s1 = 0.f, s2 = 0.f;
#pragma unroll
    for (int n = 0; n < 8; ++n) {
      hv[n] = o[n][reg] * inv;
      s1 += hv[n]; s2 += hv[n] * hv[n];
    }
    s1 += __shfl_xor(s1, 1); s1 += __shfl_xor(s1, 2);
    s1 += __shfl_xor(s1, 4); s1 += __shfl_xor(s1, 8);
    s2 += __shfl_xor(s2, 1); s2 += __shfl_xor(s2, 2);
    s2 += __shfl_xor(s2, 4); s2 += __shfl_xor(s2, 8);
    const float mu  = s1 * (1.f / 128.f);
    const float var = s2 * (1.f / 128.f) - mu * mu;
    const float rstd = rsqrtf(var + LN_EPS_C);
    float* orow = out + ((size_t)b * S_LEN + grow) * E_DIM + h * DHEAD;
#pragma unroll
    for (int n = 0; n < 8; ++n)
      orow[16 * n + r] = (hv[n] - mu) * rstd * wv_n[n];
  }
}

extern "C" void kernel_launch(void* const* d_in, const int* in_sizes, int n_in,
                              void* d_out, int out_size, void* d_ws, size_t ws_size,
                              hipStream_t stream) {
  (void)in_sizes; (void)n_in; (void)out_size;
  const float* q   = (const float*)d_in[0];
  const float* k   = (const float*)d_in[1];
  const float* v   = (const float*)d_in[2];
  const float* Wi  = (const float*)d_in[3];
  const float* bi  = (const float*)d_in[4];
  const float* Wf  = (const float*)d_in[5];
  const float* bf  = (const float*)d_in[6];
  const float* wgt = (const float*)d_in[7];
  float* out = (float*)d_out;
  float* ws  = (float*)d_ws;
  const int BNS = 2 * NHEAD * S_LEN;              // 32768
  float* ig_pre = ws;
  float* fg_pre = ws + (size_t)BNS;
  float* cs     = ws + (size_t)2 * BNS;
  float* gv     = ws + (size_t)3 * BNS;
  float* gmaxs  = ws + (size_t)4 * BNS;
  unsigned short* kb  = (unsigned short*)(ws + (size_t)5 * BNS);
  unsigned short* vtb = kb + (size_t)16 * S_LEN * DHEAD;

  const size_t need = (size_t)5 * BNS * 4 + (size_t)2 * 16 * S_LEN * DHEAD * 2;

  if (ws_size >= need) {
    gates_fused<<<512, 256, 0, stream>>>(q, k, v, Wi, bi, Wf, bf, ig_pre, fg_pre, kb);
    vtrans<<<512, 256, 0, stream>>>(v, vtb);
    scan_kernel<<<16, 256, 0, stream>>>(ig_pre, fg_pre, cs, gv, gmaxs, LNRSQ);
    mlstm_mfma4<<<512, 256, 0, stream>>>(kb, vtb, q, cs, gv, gmaxs, wgt, out);
  } else {
    gates_fused<<<512, 256, 0, stream>>>(q, k, v, Wi, bi, Wf, bf, ig_pre, fg_pre, nullptr);
    scan_kernel<<<16, 256, 0, stream>>>(ig_pre, fg_pre, cs, gv, gmaxs, 0.0f);
    mlstm_mfma<<<512, 256, 0, stream>>>(q, k, v, cs, gv, gmaxs, wgt, out);
  }
}

// Round 8
// 106.561 us; speedup vs baseline: 9.3409x; 1.0443x over previous
//
#include <hip/hip_runtime.h>
#include <math.h>

#define S_LEN 2048
#define E_DIM 1024
#define NHEAD 8
#define DHEAD 128

typedef short bf16x8 __attribute__((ext_vector_type(8)));
typedef float f32x4 __attribute__((ext_vector_type(4)));
typedef unsigned int u32x4 __attribute__((ext_vector_type(4)));
typedef unsigned int u32x2 __attribute__((ext_vector_type(2)));

constexpr float RSQ_DH  = 0.08838834764831843f; // 1/sqrt(128)
constexpr float LNRSQ   = -2.4260151319598084f; // ln(1/sqrt(128))
constexpr float EPS_NORM = 1e-6f;
constexpr float LN_EPS_C = 1e-6f;

__device__ inline unsigned bfpair(float lo, float hi) {
  unsigned a = __builtin_bit_cast(unsigned, lo);
  unsigned b = __builtin_bit_cast(unsigned, hi);
  a = (a + 0x7fffu + ((a >> 16) & 1u)) >> 16;
  b = (b + 0x7fffu + ((b >> 16) & 1u)) >> 16;
  return a | (b << 16);
}

__device__ inline unsigned cvtpk(float lo, float hi) {
  unsigned r;
  asm("v_cvt_pk_bf16_f32 %0, %1, %2" : "=v"(r) : "v"(lo), "v"(hi));
  return r;
}

__device__ inline void gload_lds16(const void* g, void* lds) {
  __builtin_amdgcn_global_load_lds(
      (const __attribute__((address_space(1))) unsigned int*)g,
      (__attribute__((address_space(3))) unsigned int*)lds, 16, 0, 0);
}
__device__ inline void gload_lds4(const void* g, void* lds) {
  __builtin_amdgcn_global_load_lds(
      (const __attribute__((address_space(1))) unsigned int*)g,
      (__attribute__((address_space(3))) unsigned int*)lds, 4, 0, 0);
}

// ---------------- Kernel 1: gates (4 rows/block, low VGPR) + bf16 K copy ----------------
__global__ __launch_bounds__(256) void gates_fused(
    const float* __restrict__ q, const float* __restrict__ k, const float* __restrict__ v,
    const float* __restrict__ Wi, const float* __restrict__ bi,
    const float* __restrict__ Wf, const float* __restrict__ bf,
    float* __restrict__ ig_pre, float* __restrict__ fg_pre,
    unsigned short* __restrict__ kb) {
  const int t = threadIdx.x;
  const int row0 = blockIdx.x * 4;
  const int b = row0 >> 11;
  const int s0 = row0 & 2047;
  float p[4][16];
#pragma unroll
  for (int rr = 0; rr < 4; ++rr)
#pragma unroll
    for (int c = 0; c < 16; ++c) p[rr][c] = 0.f;

#pragma unroll
  for (int i = 0; i < 3; ++i) {
    const float* base = (i == 0) ? q : (i == 1) ? k : v;
    float xs[4][4];
#pragma unroll
    for (int rr = 0; rr < 4; ++rr) {
      const float4 xv = *(const float4*)(base + (size_t)(row0 + rr) * E_DIM + t * 4);
      xs[rr][0] = xv.x; xs[rr][1] = xv.y; xs[rr][2] = xv.z; xs[rr][3] = xv.w;
    }
#pragma unroll
    for (int j = 0; j < 4; ++j) {
      const int ge = i * E_DIM + t * 4 + j;
      const float4 wiA = *(const float4*)(Wi + (size_t)ge * 8);
      const float4 wiB = *(const float4*)(Wi + (size_t)ge * 8 + 4);
      const float4 wfA = *(const float4*)(Wf + (size_t)ge * 8);
      const float4 wfB = *(const float4*)(Wf + (size_t)ge * 8 + 4);
      const float wv16[16] = {wiA.x, wiA.y, wiA.z, wiA.w, wiB.x, wiB.y, wiB.z, wiB.w,
                              wfA.x, wfA.y, wfA.z, wfA.w, wfB.x, wfB.y, wfB.z, wfB.w};
#pragma unroll
      for (int rr = 0; rr < 4; ++rr) {
        const float x = xs[rr][j];
#pragma unroll
        for (int c = 0; c < 16; ++c) p[rr][c] += x * wv16[c];
      }
    }
    if (i == 1 && kb != nullptr) {
      const int h = (t * 4) >> 7, d = (t * 4) & 127;
#pragma unroll
      for (int rr = 0; rr < 4; ++rr) {
        u32x2 pk;
        pk.x = bfpair(xs[rr][0], xs[rr][1]);
        pk.y = bfpair(xs[rr][2], xs[rr][3]);
        *(u32x2*)(kb + (((size_t)b * NHEAD + h) * S_LEN + (s0 + rr)) * DHEAD + d) = pk;
      }
    }
  }

#pragma unroll
  for (int rr = 0; rr < 4; ++rr)
#pragma unroll
    for (int c = 0; c < 16; ++c) {
      float val = p[rr][c];
      val += __shfl_xor(val, 1);
      val += __shfl_xor(val, 2);
      val += __shfl_xor(val, 4);
      val += __shfl_xor(val, 8);
      val += __shfl_xor(val, 16);
      val += __shfl_xor(val, 32);
      p[rr][c] = val;
    }
  __shared__ float sred[4][4][16];
  const int wid = t >> 6, lane = t & 63;
  if (lane == 0) {
#pragma unroll
    for (int rr = 0; rr < 4; ++rr)
#pragma unroll
      for (int c = 0; c < 16; ++c) sred[wid][rr][c] = p[rr][c];
  }
  __syncthreads();
  if (t < 64) {
    const int rr = t >> 4, c = t & 15;
    float sum = sred[0][rr][c] + sred[1][rr][c] + sred[2][rr][c] + sred[3][rr][c];
    const int h = c & 7;
    const int row = row0 + rr;
    const int bb = row / S_LEN, s = row % S_LEN;
    if (c < 8) ig_pre[((size_t)bb * NHEAD + h) * S_LEN + s] = sum + bi[h];
    else       fg_pre[((size_t)bb * NHEAD + h) * S_LEN + s] = sum + bf[h];
  }
}

// ---------------- Kernel 1b: V transpose to bf16 (bh, d, s) ----------------
__global__ __launch_bounds__(256) void vtrans(const float* __restrict__ v,
                                              unsigned short* __restrict__ vtb) {
  __shared__ unsigned int tile[128][36];
  const int bid = blockIdx.x;
  const int bh = bid >> 5, st = bid & 31;
  const int b = bh >> 3, h = bh & 7;
  const int s0 = st * 64;
  const int t = threadIdx.x;
#pragma unroll
  for (int i = 0; i < 4; ++i) {
    const int task = t + 256 * i;
    const int sp = task & 31, dq = task >> 5;
    const float* src = v + ((size_t)b * S_LEN + s0 + 2 * sp) * E_DIM + h * DHEAD + dq * 4;
    const float4 r0 = *(const float4*)(src);
    const float4 r1 = *(const float4*)(src + E_DIM);
    tile[dq * 4 + 0][sp] = bfpair(r0.x, r1.x);
    tile[dq * 4 + 1][sp] = bfpair(r0.y, r1.y);
    tile[dq * 4 + 2][sp] = bfpair(r0.z, r1.z);
    tile[dq * 4 + 3][sp] = bfpair(r0.w, r1.w);
  }
  __syncthreads();
#pragma unroll
  for (int i = 0; i < 2; ++i) {
    const int task = t + 256 * i;
    const int d = task >> 2, c4 = task & 3;
    u32x4 w0, w1;
    w0.x = tile[d][c4 * 8 + 0]; w0.y = tile[d][c4 * 8 + 1];
    w0.z = tile[d][c4 * 8 + 2]; w0.w = tile[d][c4 * 8 + 3];
    w1.x = tile[d][c4 * 8 + 4]; w1.y = tile[d][c4 * 8 + 5];
    w1.z = tile[d][c4 * 8 + 6]; w1.w = tile[d][c4 * 8 + 7];
    unsigned short* dst = vtb + ((size_t)bh * DHEAD + d) * S_LEN + s0 + c4 * 16;
    *(u32x4*)(dst)     = w0;
    *(u32x4*)(dst + 8) = w1;
  }
}

// ---------------- Kernel 2: log-sigmoid + cumsum + prefix-max ----------------
__global__ __launch_bounds__(256) void scan_kernel(
    const float* __restrict__ ig_pre, const float* __restrict__ fg_pre,
    float* __restrict__ cs_out, float* __restrict__ g_out, float* __restrict__ gmax_out,
    float g_add) {
  const int bhh = blockIdx.x;
  const int t = threadIdx.x;
  const size_t base = (size_t)bhh * S_LEN;
  float vals[8];
  float run = 0.f;
#pragma unroll
  for (int i = 0; i < 8; ++i) {
    const float x = fg_pre[base + t * 8 + i];
    const float lf = fminf(x, 0.f) - log1pf(__expf(-fabsf(x)));
    run += lf;
    vals[i] = run;
  }
  __shared__ float sums[256];
  sums[t] = run;
  __syncthreads();
  for (int off = 1; off < 256; off <<= 1) {
    const float other = (t >= off) ? sums[t - off] : 0.f;
    __syncthreads();
    sums[t] += other;
    __syncthreads();
  }
  const float prefix = (t > 0) ? sums[t - 1] : 0.f;
  float g_loc[8], gm_loc[8];
  float lmax = -3.4e38f;
#pragma unroll
  for (int i = 0; i < 8; ++i) {
    const float csv = vals[i] + prefix;
    vals[i] = csv;
    const float gg = ig_pre[base + t * 8 + i] - csv;
    g_loc[i] = gg;
    lmax = fmaxf(lmax, gg);
    gm_loc[i] = lmax;
  }
  __shared__ float maxs[256];
  maxs[t] = lmax;
  __syncthreads();
  for (int off = 1; off < 256; off <<= 1) {
    const float other = (t >= off) ? maxs[t - off] : -3.4e38f;
    __syncthreads();
    maxs[t] = fmaxf(maxs[t], other);
    __syncthreads();
  }
  const float pmax = (t > 0) ? maxs[t - 1] : -3.4e38f;
#pragma unroll
  for (int i = 0; i < 8; ++i) {
    cs_out[base + t * 8 + i]   = vals[i];
    g_out[base + t * 8 + i]    = g_loc[i] + g_add;
    gmax_out[base + t * 8 + i] = fmaxf(gm_loc[i], pmax);
  }
}

// ---------------- Kernel 3 (fast): 8-wave split-K blocks, KVB=32, dbuf + counted vmcnt ----------------
// Block: (bh, qb) with 64 q-rows, 8 waves. Wave = (team tp = w>>2, i-group ig = w&3).
// Team 0 computes even 32-j tiles, team 1 odd tiles, concurrently in separate buffers.
// Per pair-stage: 5 vmem ops/wave (2 K + 2 V + 1 g).
__global__ __launch_bounds__(512, 4) void mlstm_mfma8(
    const unsigned short* __restrict__ kb, const unsigned short* __restrict__ vtb,
    const float* __restrict__ q,
    const float* __restrict__ cs, const float* __restrict__ garr, const float* __restrict__ gmax,
    const float* __restrict__ wgt, float* __restrict__ out) {
  __shared__ __align__(16) unsigned char kbuf[4][8192];  // [set*2+team]: K 32x128 bf16 (swizzled)
  __shared__ __align__(16) unsigned char vbuf[4][8192];  // [set*2+team]: V^T 128x32 bf16 (swizzled)
  __shared__ float g_sh[4][32];
  __shared__ float den_sh[4][64];

  const int bid = blockIdx.x;
  int qb;
  if (bid < 256) qb = 31 - (bid >> 4);      // heavy-first; CU pairs qb with 31-qb
  else           qb = (bid - 256) >> 4;
  const int g16 = bid & 15;
  const int bh = 2 * (g16 & 7) + (g16 >> 3);   // same-bh blocks on same XCD
  const int b = bh >> 3, h = bh & 7;
  const int t = threadIdx.x;
  const int w = t >> 6;          // 0..7
  const int ig = w & 3;          // i-group (q-row interleave)
  const int tp = w >> 2;         // j-parity team
  const int l = t & 63;
  const int r = l & 15;
  const int qq = l >> 4;
  const size_t bhS = (size_t)bh * S_LEN;

  const int gr = qb * 64 + 4 * r + ig;         // lane's q-row
  const float gm_lane = gmax[bhS + gr];

  // Q fragment (B-operand): qfrag[c] = Q[i=r][d = 32c + 8qq + e]
  bf16x8 qfrag[4];
  {
    const float* qrow = q + ((size_t)b * S_LEN + gr) * E_DIM + h * DHEAD;
#pragma unroll
    for (int c = 0; c < 4; ++c) {
      const float4 f0 = *(const float4*)(qrow + 32 * c + 8 * qq);
      const float4 f1 = *(const float4*)(qrow + 32 * c + 8 * qq + 4);
      u32x4 u;
      u.x = bfpair(f0.x, f0.y); u.y = bfpair(f0.z, f0.w);
      u.z = bfpair(f1.x, f1.y); u.w = bfpair(f1.z, f1.w);
      qfrag[c] = __builtin_bit_cast(bf16x8, u);
    }
  }

  f32x4 o[8];
#pragma unroll
  for (int n = 0; n < 8; ++n) o[n] = (f32x4){0.f, 0.f, 0.f, 0.f};
  float den_p = 0.f;

  const unsigned short* kt = kb + bhS * DHEAD;
  const unsigned short* vt = vtb + (size_t)bh * DHEAD * S_LEN;

  // ---- stage this team's tile of `pair` into buffer set: 5 vmem ops per wave ----
  auto stage = [&](int pair, int set) {
    const int j0 = pair * 64 + tp * 32;
    const int bi = set * 2 + tp;
#pragma unroll
    for (int a = 0; a < 2; ++a) {
      const int m = ig * 128 + a * 64 + l;      // physical 16B unit (0..511)
      const int u = m ^ ((m >> 4) & 7);         // logical unit (involution)
      gload_lds16(kt + ((size_t)(j0 + (u >> 4))) * DHEAD + (u & 15) * 8,
                  &kbuf[bi][(ig * 128 + a * 64) * 16]);
    }
#pragma unroll
    for (int a = 0; a < 2; ++a) {
      const int m = ig * 128 + a * 64 + l;
      const int u = m ^ ((m >> 3) & 7);
      gload_lds16(vt + (size_t)(u >> 2) * S_LEN + j0 + (u & 3) * 8,
                  &vbuf[bi][(ig * 128 + a * 64) * 16]);
    }
    // g tile (32 floats): per-lane source, lanes 0..31 only
    if (l < 32) gload_lds4(garr + bhS + j0 + l, &g_sh[bi][0]);
  };

  // ---- per-tile compute on buffer bi ----
  auto body = [&](int j0, int bi, bool diag) {
    __builtin_amdgcn_s_setprio(1);
    f32x4 st0 = {0, 0, 0, 0}, st1 = {0, 0, 0, 0};
#pragma unroll
    for (int c = 0; c < 4; ++c) {
      const int u0 = ((r)      * 16 + 4 * c + qq) ^ (r & 7);
      const int u1 = ((16 + r) * 16 + 4 * c + qq) ^ (r & 7);
      bf16x8 ka0 = *(const bf16x8*)&kbuf[bi][u0 * 16];
      bf16x8 ka1 = *(const bf16x8*)&kbuf[bi][u1 * 16];
      st0 = __builtin_amdgcn_mfma_f32_16x16x32_bf16(ka0, qfrag[c], st0, 0, 0, 0);
      st1 = __builtin_amdgcn_mfma_f32_16x16x32_bf16(ka1, qfrag[c], st1, 0, 0, 0);
    }
    __builtin_amdgcn_s_setprio(0);

    // gated weights w[i=r][j=16g+4qq+m] (1/sqrt(DH) folded into garr)
    unsigned P0[2], P1[2];
    {
      float wv[4];
#pragma unroll
      for (int m = 0; m < 4; ++m) {
        const int jl = 4 * qq + m;
        float ww = st0[m] * __expf(g_sh[bi][jl] - gm_lane);
        if (diag && (j0 + jl > gr)) ww = 0.f;
        wv[m] = ww; den_p += ww;
      }
      P0[0] = cvtpk(wv[0], wv[1]); P0[1] = cvtpk(wv[2], wv[3]);
#pragma unroll
      for (int m = 0; m < 4; ++m) {
        const int jl = 16 + 4 * qq + m;
        float ww = st1[m] * __expf(g_sh[bi][jl] - gm_lane);
        if (diag && (j0 + jl > gr)) ww = 0.f;
        wv[m] = ww; den_p += ww;
      }
      P1[0] = cvtpk(wv[0], wv[1]); P1[1] = cvtpk(wv[2], wv[3]);
    }

    // in-register exchange: C-layout -> A-fragment (j = 8qq + 0..7)
    unsigned A0[4];
#pragma unroll
    for (int m = 0; m < 4; ++m) {
      const int srcl = r + 16 * (2 * (qq & 1) + (m >> 1));
      const unsigned x0 = (unsigned)__shfl((int)P0[m & 1], srcl);
      const unsigned x1 = (unsigned)__shfl((int)P1[m & 1], srcl);
      A0[m] = (qq < 2) ? x0 : x1;
    }
    u32x4 ua;
    ua.x = A0[0]; ua.y = A0[1]; ua.z = A0[2]; ua.w = A0[3];
    const bf16x8 pa = __builtin_bit_cast(bf16x8, ua);

    // PV: O[i][d] += w . V over this 32-j chunk
    __builtin_amdgcn_s_setprio(1);
#pragma unroll
    for (int n = 0; n < 8; ++n) {
      const int ud = (16 * n + r) * 4 + qq;
      const int up = ud ^ ((ud >> 3) & 7);
      bf16x8 vb = *(const bf16x8*)&vbuf[bi][up * 16];
      o[n] = __builtin_amdgcn_mfma_f32_16x16x32_bf16(pa, vb, o[n], 0, 0, 0);
    }
    __builtin_amdgcn_s_setprio(0);
  };

  stage(0, 0);
  for (int p = 0; p < qb; ++p) {
    stage(p + 1, (p + 1) & 1);
    asm volatile("s_waitcnt vmcnt(5)" ::: "memory");  // pair p drained, p+1 in flight
    __builtin_amdgcn_sched_barrier(0);
    __syncthreads();
    body(p * 64 + tp * 32, (p & 1) * 2 + tp, false);
    __syncthreads();
  }
  // last pair (diagonal tiles for both teams)
  asm volatile("s_waitcnt vmcnt(0)" ::: "memory");
  __builtin_amdgcn_sched_barrier(0);
  __syncthreads();
  body(qb * 64 + tp * 32, (qb & 1) * 2 + tp, true);

  // ---- split-K merge: team1 -> LDS, team0 accumulates ----
  float* osh = (float*)&kbuf[0][0];   // 32 KB, buffers dead now
  __syncthreads();
  if (tp == 1) {
#pragma unroll
    for (int n = 0; n < 8; ++n)
      *(f32x4*)&osh[(((n << 2) + ig) * 64 + l) * 4] = o[n];
    den_sh[ig][l] = den_p;
  }
  __syncthreads();
  if (tp == 0) {
    den_p += den_sh[ig][l];
#pragma unroll
    for (int n = 0; n < 8; ++n)
      o[n] += *(const f32x4*)&osh[(((n << 2) + ig) * 64 + l) * 4];

    // ---- epilogue: normalizer + per-head LayerNorm + store ----
    float den_f = den_p;
    den_f += __shfl_xor(den_f, 16);
    den_f += __shfl_xor(den_f, 32);

    const float* wrow = wgt + h * DHEAD;
    float wv_n[8];
#pragma unroll
    for (int n = 0; n < 8; ++n) wv_n[n] = wrow[16 * n + r];

#pragma unroll
    for (int m = 0; m < 4; ++m) {
      const int iloc = 4 * qq + m;
      const float den_o = __shfl(den_f, iloc);
      const int grow = qb * 64 + 4 * iloc + ig;
      const float csg = cs[bhS + grow];
      const float gmg = gmax[bhS + grow];
      const float norm = fmaxf(fabsf(den_o), __expf(-(csg + gmg))) + EPS_NORM;
      const float inv = 1.f / norm;
      float hv[8];
      float s1 = 0.f, s2 = 0.f;
#pragma unroll
      for (int n = 0; n < 8; ++n) {
        hv[n] = o[n][m] * inv;
        s1 += hv[n]; s2 += hv[n] * hv[n];
      }
      s1 += __shfl_xor(s1, 1); s1 += __shfl_xor(s1, 2);
      s1 += __shfl_xor(s1, 4); s1 += __shfl_xor(s1, 8);
      s2 += __shfl_xor(s2, 1); s2 += __shfl_xor(s2, 2);
      s2 += __shfl_xor(s2, 4); s2 += __shfl_xor(s2, 8);
      const float mu  = s1 * (1.f / 128.f);
      const float var = s2 * (1.f / 128.f) - mu * mu;
      const float rstd = rsqrtf(var + LN_EPS_C);
      float* orow = out + ((size_t)b * S_LEN + grow) * E_DIM + h * DHEAD;
#pragma unroll
      for (int n = 0; n < 8; ++n)
        orow[16 * n + r] = (hv[n] - mu) * rstd * wv_n[n];
    }
  }
}

// ---------------- Kernel 3 (fallback, round-2 verified): fp32 staged in-loop ----------------
__global__ __launch_bounds__(256) void mlstm_mfma(
    const float* __restrict__ q, const float* __restrict__ k, const float* __restrict__ v,
    const float* __restrict__ cs, const float* __restrict__ garr, const float* __restrict__ gmax,
    const float* __restrict__ wgt, float* __restrict__ out) {
  __shared__ unsigned short k_lds[32][136];
  __shared__ unsigned int   vt_u32[128][20];
  __shared__ unsigned int   xch[4][16][20];
  __shared__ float          g_sh[32];

  const int bid = blockIdx.x;
  int qt;
  if (bid < 256) qt = 31 - (bid >> 4);
  else           qt = (bid - 256) >> 4;
  const int bh = bid & 15;
  const int b = bh >> 3, h = bh & 7;
  const int t = threadIdx.x;
  const int w = t >> 6;
  const int l = t & 63;
  const int r = l & 15;
  const int qq = l >> 4;
  const size_t bhS = (size_t)bh * S_LEN;

  const int gr = qt * 64 + 4 * r + w;
  const float gm_lane = gmax[bhS + gr];

  bf16x8 qfrag[4];
  {
    const float* qrow = q + ((size_t)b * S_LEN + gr) * E_DIM + h * DHEAD;
#pragma unroll
    for (int c = 0; c < 4; ++c) {
      const float4 f0 = *(const float4*)(qrow + 32 * c + 8 * qq);
      const float4 f1 = *(const float4*)(qrow + 32 * c + 8 * qq + 4);
      u32x4 u;
      u.x = bfpair(f0.x, f0.y); u.y = bfpair(f0.z, f0.w);
      u.z = bfpair(f1.x, f1.y); u.w = bfpair(f1.z, f1.w);
      qfrag[c] = __builtin_bit_cast(bf16x8, u);
    }
  }

  f32x4 o[8];
#pragma unroll
  for (int n = 0; n < 8; ++n) o[n] = (f32x4){0.f, 0.f, 0.f, 0.f};
  float den_p = 0.f;

  const int kj = t >> 3, ks = t & 7;
  const int vjp = t & 15, vds = t >> 4;

  const int ntiles = 2 * qt + 2;
  for (int jt = 0; jt < ntiles; ++jt) {
    const int j0 = jt * 32;
    {
      const float* src = k + ((size_t)b * S_LEN + j0 + kj) * E_DIM + h * DHEAD + ks * 16;
      float4 f0 = *(const float4*)(src);
      float4 f1 = *(const float4*)(src + 4);
      float4 f2 = *(const float4*)(src + 8);
      float4 f3 = *(const float4*)(src + 12);
      u32x4 ua, ub;
      ua.x = bfpair(f0.x, f0.y); ua.y = bfpair(f0.z, f0.w);
      ua.z = bfpair(f1.x, f1.y); ua.w = bfpair(f1.z, f1.w);
      ub.x = bfpair(f2.x, f2.y); ub.y = bfpair(f2.z, f2.w);
      ub.z = bfpair(f3.x, f3.y); ub.w = bfpair(f3.z, f3.w);
      *(u32x4*)&k_lds[kj][ks * 16]     = ua;
      *(u32x4*)&k_lds[kj][ks * 16 + 8] = ub;
    }
    {
      const float* s0 = v + ((size_t)b * S_LEN + j0 + 2 * vjp) * E_DIM + h * DHEAD + vds * 8;
      const float* s1 = s0 + E_DIM;
      float4 a0 = *(const float4*)(s0);
      float4 a1 = *(const float4*)(s0 + 4);
      float4 b0 = *(const float4*)(s1);
      float4 b1 = *(const float4*)(s1 + 4);
      vt_u32[vds * 8 + 0][vjp] = bfpair(a0.x, b0.x);
      vt_u32[vds * 8 + 1][vjp] = bfpair(a0.y, b0.y);
      vt_u32[vds * 8 + 2][vjp] = bfpair(a0.z, b0.z);
      vt_u32[vds * 8 + 3][vjp] = bfpair(a0.w, b0.w);
      vt_u32[vds * 8 + 4][vjp] = bfpair(a1.x, b1.x);
      vt_u32[vds * 8 + 5][vjp] = bfpair(a1.y, b1.y);
      vt_u32[vds * 8 + 6][vjp] = bfpair(a1.z, b1.z);
      vt_u32[vds * 8 + 7][vjp] = bfpair(a1.w, b1.w);
    }
    if (t < 32) g_sh[t] = garr[bhS + j0 + t];
    __syncthreads();

    f32x4 st0 = {0, 0, 0, 0}, st1 = {0, 0, 0, 0};
#pragma unroll
    for (int c = 0; c < 4; ++c) {
      bf16x8 ka0 = *(const bf16x8*)&k_lds[r][32 * c + 8 * qq];
      bf16x8 ka1 = *(const bf16x8*)&k_lds[16 + r][32 * c + 8 * qq];
      st0 = __builtin_amdgcn_mfma_f32_16x16x32_bf16(ka0, qfrag[c], st0, 0, 0, 0);
      st1 = __builtin_amdgcn_mfma_f32_16x16x32_bf16(ka1, qfrag[c], st1, 0, 0, 0);
    }

    const bool diag = (jt >= 2 * qt);
    float wv0[4], wv1[4];
#pragma unroll
    for (int reg = 0; reg < 4; ++reg) {
      const int jl0 = 4 * qq + reg, jl1 = 16 + 4 * qq + reg;
      const float e0 = __expf(g_sh[jl0] - gm_lane);
      const float e1 = __expf(g_sh[jl1] - gm_lane);
      float w0 = st0[reg] * RSQ_DH * e0;
      float w1 = st1[reg] * RSQ_DH * e1;
      if (diag) {
        if (j0 + jl0 > gr) w0 = 0.f;
        if (j0 + jl1 > gr) w1 = 0.f;
      }
      wv0[reg] = w0; wv1[reg] = w1;
      den_p += w0 + w1;
    }

    u32x2 p0, p1;
    p0.x = bfpair(wv0[0], wv0[1]); p0.y = bfpair(wv0[2], wv0[3]);
    p1.x = bfpair(wv1[0], wv1[1]); p1.y = bfpair(wv1[2], wv1[3]);
    *(u32x2*)&xch[w][r][2 * qq]     = p0;
    *(u32x2*)&xch[w][r][8 + 2 * qq] = p1;
    __builtin_amdgcn_wave_barrier();
    bf16x8 pa = *(const bf16x8*)&xch[w][r][4 * qq];
    __builtin_amdgcn_wave_barrier();

#pragma unroll
    for (int n = 0; n < 8; ++n) {
      bf16x8 vb = *(const bf16x8*)&vt_u32[16 * n + r][4 * qq];
      o[n] = __builtin_amdgcn_mfma_f32_16x16x32_bf16(pa, vb, o[n], 0, 0, 0);
    }
    __syncthreads();
  }

  float den_f = den_p;
  den_f += __shfl_xor(den_f, 16);
  den_f += __shfl_xor(den_f, 32);

  const float* wrow = wgt + h * DHEAD;
  float wv_n[8];
#pragma unroll
  for (int n = 0; n < 8; ++n) wv_n[n] = wrow[16 * n + r];

#pragma unroll
  for (int reg = 0; reg < 4; ++reg) {
    const int iloc = 4 * qq + reg;
    const float den_o = __shfl(den_f, iloc);
    const int grow = qt * 64 + 4 * iloc + w;
    const float csg = cs[bhS + grow];
    const float gmg = gmax[bhS + grow];
    const float norm = fmaxf(fabsf(den_o), __expf(-(csg + gmg))) + EPS_NORM;
    const float inv = 1.f / norm;
    float hv[8];
    float s1 = 0.f, s2 = 0.f;
#pragma unroll
    for (int n = 0; n < 8; ++n) {
      hv[n] = o[n][reg] * inv;
      s1 += hv[n]; s2 += hv[n] * hv[n];
    }
    s1 += __shfl_xor(s1, 1); s1 += __shfl_xor(s1, 2);
    s1 += __shfl_xor(s1, 4); s1 += __shfl_xor(s1, 8);
    s2 += __shfl_xor(s2, 1); s2 += __shfl_xor(s2, 2);
    s2 += __shfl_xor(s2, 4); s2 += __shfl_xor(s2, 8);
    const float mu  = s1 * (1.f / 128.f);
    const float var = s2 * (1.f / 128.f) - mu * mu;
    const float rstd = rsqrtf(var + LN_EPS_C);
    float* orow = out + ((size_t)b * S_LEN + grow) * E_DIM + h * DHEAD;
#pragma unroll
    for (int n = 0; n < 8; ++n)
      orow[16 * n + r] = (hv[n] - mu) * rstd * wv_n[n];
  }
}

extern "C" void kernel_launch(void* const* d_in, const int* in_sizes, int n_in,
                              void* d_out, int out_size, void* d_ws, size_t ws_size,
                              hipStream_t stream) {
  (void)in_sizes; (void)n_in; (void)out_size;
  const float* q   = (const float*)d_in[0];
  const float* k   = (const float*)d_in[1];
  const float* v   = (const float*)d_in[2];
  const float* Wi  = (const float*)d_in[3];
  const float* bi  = (const float*)d_in[4];
  const float* Wf  = (const float*)d_in[5];
  const float* bf  = (const float*)d_in[6];
  const float* wgt = (const float*)d_in[7];
  float* out = (float*)d_out;
  float* ws  = (float*)d_ws;
  const int BNS = 2 * NHEAD * S_LEN;              // 32768
  float* ig_pre = ws;
  float* fg_pre = ws + (size_t)BNS;
  float* cs     = ws + (size_t)2 * BNS;
  float* gv     = ws + (size_t)3 * BNS;
  float* gmaxs  = ws + (size_t)4 * BNS;
  unsigned short* kb  = (unsigned short*)(ws + (size_t)5 * BNS);
  unsigned short* vtb = kb + (size_t)16 * S_LEN * DHEAD;

  const size_t need = (size_t)5 * BNS * 4 + (size_t)2 * 16 * S_LEN * DHEAD * 2;

  if (ws_size >= need) {
    gates_fused<<<1024, 256, 0, stream>>>(q, k, v, Wi, bi, Wf, bf, ig_pre, fg_pre, kb);
    vtrans<<<512, 256, 0, stream>>>(v, vtb);
    scan_kernel<<<16, 256, 0, stream>>>(ig_pre, fg_pre, cs, gv, gmaxs, LNRSQ);
    mlstm_mfma8<<<512, 512, 0, stream>>>(kb, vtb, q, cs, gv, gmaxs, wgt, out);
  } else {
    gates_fused<<<1024, 256, 0, stream>>>(q, k, v, Wi, bi, Wf, bf, ig_pre, fg_pre, nullptr);
    scan_kernel<<<16, 256, 0, stream>>>(ig_pre, fg_pre, cs, gv, gmaxs, 0.0f);
    mlstm_mfma<<<512, 256, 0, stream>>>(q, k, v, cs, gv, gmaxs, wgt, out);
  }
}

// Round 9
// 102.082 us; speedup vs baseline: 9.7506x; 1.0439x over previous
//
#include <hip/hip_runtime.h>
#include <math.h>

#define S_LEN 2048
#define E_DIM 1024
#define NHEAD 8
#define DHEAD 128

typedef short bf16x8 __attribute__((ext_vector_type(8)));
typedef float f32x4 __attribute__((ext_vector_type(4)));
typedef unsigned int u32x4 __attribute__((ext_vector_type(4)));
typedef unsigned int u32x2 __attribute__((ext_vector_type(2)));

constexpr float RSQ_DH  = 0.08838834764831843f; // 1/sqrt(128)
constexpr float LNRSQ   = -2.4260151319598084f; // ln(1/sqrt(128))
constexpr float EPS_NORM = 1e-6f;
constexpr float LN_EPS_C = 1e-6f;

__device__ inline unsigned bfpair(float lo, float hi) {
  unsigned a = __builtin_bit_cast(unsigned, lo);
  unsigned b = __builtin_bit_cast(unsigned, hi);
  a = (a + 0x7fffu + ((a >> 16) & 1u)) >> 16;
  b = (b + 0x7fffu + ((b >> 16) & 1u)) >> 16;
  return a | (b << 16);
}

__device__ inline unsigned cvtpk(float lo, float hi) {
  unsigned r;
  asm("v_cvt_pk_bf16_f32 %0, %1, %2" : "=v"(r) : "v"(lo), "v"(hi));
  return r;
}

__device__ inline void gload_lds16(const void* g, void* lds) {
  __builtin_amdgcn_global_load_lds(
      (const __attribute__((address_space(1))) unsigned int*)g,
      (__attribute__((address_space(3))) unsigned int*)lds, 16, 0, 0);
}
__device__ inline void gload_lds4(const void* g, void* lds) {
  __builtin_amdgcn_global_load_lds(
      (const __attribute__((address_space(1))) unsigned int*)g,
      (__attribute__((address_space(3))) unsigned int*)lds, 4, 0, 0);
}

// ---------------- Kernel 1: gates (4 rows/block, low VGPR) + bf16 K copy ----------------
__global__ __launch_bounds__(256) void gates_fused(
    const float* __restrict__ q, const float* __restrict__ k, const float* __restrict__ v,
    const float* __restrict__ Wi, const float* __restrict__ bi,
    const float* __restrict__ Wf, const float* __restrict__ bf,
    float* __restrict__ ig_pre, float* __restrict__ fg_pre,
    unsigned short* __restrict__ kb) {
  const int t = threadIdx.x;
  const int row0 = blockIdx.x * 4;
  const int b = row0 >> 11;
  const int s0 = row0 & 2047;
  float p[4][16];
#pragma unroll
  for (int rr = 0; rr < 4; ++rr)
#pragma unroll
    for (int c = 0; c < 16; ++c) p[rr][c] = 0.f;

#pragma unroll
  for (int i = 0; i < 3; ++i) {
    const float* base = (i == 0) ? q : (i == 1) ? k : v;
    float xs[4][4];
#pragma unroll
    for (int rr = 0; rr < 4; ++rr) {
      const float4 xv = *(const float4*)(base + (size_t)(row0 + rr) * E_DIM + t * 4);
      xs[rr][0] = xv.x; xs[rr][1] = xv.y; xs[rr][2] = xv.z; xs[rr][3] = xv.w;
    }
#pragma unroll
    for (int j = 0; j < 4; ++j) {
      const int ge = i * E_DIM + t * 4 + j;
      const float4 wiA = *(const float4*)(Wi + (size_t)ge * 8);
      const float4 wiB = *(const float4*)(Wi + (size_t)ge * 8 + 4);
      const float4 wfA = *(const float4*)(Wf + (size_t)ge * 8);
      const float4 wfB = *(const float4*)(Wf + (size_t)ge * 8 + 4);
      const float wv16[16] = {wiA.x, wiA.y, wiA.z, wiA.w, wiB.x, wiB.y, wiB.z, wiB.w,
                              wfA.x, wfA.y, wfA.z, wfA.w, wfB.x, wfB.y, wfB.z, wfB.w};
#pragma unroll
      for (int rr = 0; rr < 4; ++rr) {
        const float x = xs[rr][j];
#pragma unroll
        for (int c = 0; c < 16; ++c) p[rr][c] += x * wv16[c];
      }
    }
    if (i == 1 && kb != nullptr) {
      const int h = (t * 4) >> 7, d = (t * 4) & 127;
#pragma unroll
      for (int rr = 0; rr < 4; ++rr) {
        u32x2 pk;
        pk.x = bfpair(xs[rr][0], xs[rr][1]);
        pk.y = bfpair(xs[rr][2], xs[rr][3]);
        *(u32x2*)(kb + (((size_t)b * NHEAD + h) * S_LEN + (s0 + rr)) * DHEAD + d) = pk;
      }
    }
  }

#pragma unroll
  for (int rr = 0; rr < 4; ++rr)
#pragma unroll
    for (int c = 0; c < 16; ++c) {
      float val = p[rr][c];
      val += __shfl_xor(val, 1);
      val += __shfl_xor(val, 2);
      val += __shfl_xor(val, 4);
      val += __shfl_xor(val, 8);
      val += __shfl_xor(val, 16);
      val += __shfl_xor(val, 32);
      p[rr][c] = val;
    }
  __shared__ float sred[4][4][16];
  const int wid = t >> 6, lane = t & 63;
  if (lane == 0) {
#pragma unroll
    for (int rr = 0; rr < 4; ++rr)
#pragma unroll
      for (int c = 0; c < 16; ++c) sred[wid][rr][c] = p[rr][c];
  }
  __syncthreads();
  if (t < 64) {
    const int rr = t >> 4, c = t & 15;
    float sum = sred[0][rr][c] + sred[1][rr][c] + sred[2][rr][c] + sred[3][rr][c];
    const int h = c & 7;
    const int row = row0 + rr;
    const int bb = row / S_LEN, s = row % S_LEN;
    if (c < 8) ig_pre[((size_t)bb * NHEAD + h) * S_LEN + s] = sum + bi[h];
    else       fg_pre[((size_t)bb * NHEAD + h) * S_LEN + s] = sum + bf[h];
  }
}

// ---------------- Kernel 1b: V transpose to bf16 (bh, d, s) ----------------
__global__ __launch_bounds__(256) void vtrans(const float* __restrict__ v,
                                              unsigned short* __restrict__ vtb) {
  __shared__ unsigned int tile[128][36];
  const int bid = blockIdx.x;
  const int bh = bid >> 5, st = bid & 31;
  const int b = bh >> 3, h = bh & 7;
  const int s0 = st * 64;
  const int t = threadIdx.x;
#pragma unroll
  for (int i = 0; i < 4; ++i) {
    const int task = t + 256 * i;
    const int sp = task & 31, dq = task >> 5;
    const float* src = v + ((size_t)b * S_LEN + s0 + 2 * sp) * E_DIM + h * DHEAD + dq * 4;
    const float4 r0 = *(const float4*)(src);
    const float4 r1 = *(const float4*)(src + E_DIM);
    tile[dq * 4 + 0][sp] = bfpair(r0.x, r1.x);
    tile[dq * 4 + 1][sp] = bfpair(r0.y, r1.y);
    tile[dq * 4 + 2][sp] = bfpair(r0.z, r1.z);
    tile[dq * 4 + 3][sp] = bfpair(r0.w, r1.w);
  }
  __syncthreads();
#pragma unroll
  for (int i = 0; i < 2; ++i) {
    const int task = t + 256 * i;
    const int d = task >> 2, c4 = task & 3;
    u32x4 w0, w1;
    w0.x = tile[d][c4 * 8 + 0]; w0.y = tile[d][c4 * 8 + 1];
    w0.z = tile[d][c4 * 8 + 2]; w0.w = tile[d][c4 * 8 + 3];
    w1.x = tile[d][c4 * 8 + 4]; w1.y = tile[d][c4 * 8 + 5];
    w1.z = tile[d][c4 * 8 + 6]; w1.w = tile[d][c4 * 8 + 7];
    unsigned short* dst = vtb + ((size_t)bh * DHEAD + d) * S_LEN + s0 + c4 * 16;
    *(u32x4*)(dst)     = w0;
    *(u32x4*)(dst + 8) = w1;
  }
}

// ---------------- Kernel 2: log-sigmoid + cumsum + prefix-max (shfl scans, 2 barriers) ----------------
__global__ __launch_bounds__(256) void scan_kernel(
    const float* __restrict__ ig_pre, const float* __restrict__ fg_pre,
    float* __restrict__ cs_out, float* __restrict__ g_out, float* __restrict__ gmax_out,
    float g_add) {
  const int bhh = blockIdx.x;
  const int t = threadIdx.x;
  const int lane = t & 63, wid = t >> 6;
  const size_t base = (size_t)bhh * S_LEN;
  float vals[8];
  float run = 0.f;
#pragma unroll
  for (int i = 0; i < 8; ++i) {
    const float x = fg_pre[base + t * 8 + i];
    const float lf = fminf(x, 0.f) - log1pf(__expf(-fabsf(x)));
    run += lf;
    vals[i] = run;
  }
  // wave inclusive scan of per-thread sums
  float ws = run;
#pragma unroll
  for (int off = 1; off < 64; off <<= 1) {
    const float v = __shfl_up(ws, off);
    if (lane >= off) ws += v;
  }
  __shared__ float wsum[4];
  if (lane == 63) wsum[wid] = ws;
  __syncthreads();
  float wpre = 0.f;
#pragma unroll
  for (int kk = 0; kk < 4; ++kk)
    if (kk < wid) wpre += wsum[kk];
  const float prefix = wpre + (ws - run);   // exclusive prefix for this thread

  float g_loc[8], gm_loc[8];
  float lmax = -3.4e38f;
#pragma unroll
  for (int i = 0; i < 8; ++i) {
    const float csv = vals[i] + prefix;
    vals[i] = csv;
    const float gg = ig_pre[base + t * 8 + i] - csv;
    g_loc[i] = gg;
    lmax = fmaxf(lmax, gg);
    gm_loc[i] = lmax;
  }
  // wave inclusive max-scan of per-thread maxima
  float wm = lmax;
#pragma unroll
  for (int off = 1; off < 64; off <<= 1) {
    const float v = __shfl_up(wm, off);
    if (lane >= off) wm = fmaxf(wm, v);
  }
  __shared__ float wmax[4];
  if (lane == 63) wmax[wid] = wm;
  __syncthreads();
  float mpre = -3.4e38f;
#pragma unroll
  for (int kk = 0; kk < 4; ++kk)
    if (kk < wid) mpre = fmaxf(mpre, wmax[kk]);
  float excl = __shfl_up(wm, 1);
  if (lane == 0) excl = -3.4e38f;
  const float pmax = fmaxf(mpre, excl);     // exclusive prefix-max for this thread

#pragma unroll
  for (int i = 0; i < 8; ++i) {
    cs_out[base + t * 8 + i]   = vals[i];
    g_out[base + t * 8 + i]    = g_loc[i] + g_add;
    gmax_out[base + t * 8 + i] = fmaxf(gm_loc[i], pmax);
  }
}

// ---------------- Kernel 3 (fast): 4 waves, 32 q-rows/wave (dual fragment), split-K teams ----------------
// Block: (bh, qb), 64 q-rows. Wave = (team tp = w>>1, sub iw = w&1); rows gr = qb*64+4r+2iw+fg.
// Each K/V LDS read feeds TWO MFMAs (fragments A,B) -> LDS read traffic halved vs r8.
__global__ __launch_bounds__(256) void mlstm_mfma9(
    const unsigned short* __restrict__ kb, const unsigned short* __restrict__ vtb,
    const float* __restrict__ q,
    const float* __restrict__ cs, const float* __restrict__ garr, const float* __restrict__ gmax,
    const float* __restrict__ wgt, float* __restrict__ out) {
  __shared__ __align__(16) unsigned char kbuf[4][8192];  // [set*2+team]: K 32x128 bf16 (swizzled)
  __shared__ __align__(16) unsigned char vbuf[4][8192];  // [set*2+team]: V^T 128x32 bf16 (swizzled)
  __shared__ float g_sh[4][32];
  __shared__ float den_sh[4][64];

  const int bid = blockIdx.x;
  int qb;
  if (bid < 256) qb = 31 - (bid >> 4);      // heavy-first; CU pairs qb with 31-qb
  else           qb = (bid - 256) >> 4;
  const int g16 = bid & 15;
  const int bh = 2 * (g16 & 7) + (g16 >> 3);   // same-bh blocks on same XCD
  const int b = bh >> 3, h = bh & 7;
  const int t = threadIdx.x;
  const int w = t >> 6;          // 0..3
  const int iw = w & 1;          // i-subgroup
  const int tp = w >> 1;         // j-parity team
  const int l = t & 63;
  const int r = l & 15;
  const int qq = l >> 4;
  const size_t bhS = (size_t)bh * S_LEN;

  const int grA = qb * 64 + 4 * r + 2 * iw;    // fragment A q-row
  const int grB = grA + 1;                     // fragment B q-row
  const float gmA = gmax[bhS + grA];
  const float gmB = gmax[bhS + grB];
  const float rAB = __expf(gmA - gmB);         // expB = expA * rAB (gmB >= gmA-ish, adjacent rows)

  // Q fragments (B-operand): qf[c] = Q[i=r][d = 32c + 8qq + e]
  bf16x8 qfA[4], qfB[4];
  {
    const float* qrowA = q + ((size_t)b * S_LEN + grA) * E_DIM + h * DHEAD;
    const float* qrowB = q + ((size_t)b * S_LEN + grB) * E_DIM + h * DHEAD;
#pragma unroll
    for (int c = 0; c < 4; ++c) {
      float4 f0 = *(const float4*)(qrowA + 32 * c + 8 * qq);
      float4 f1 = *(const float4*)(qrowA + 32 * c + 8 * qq + 4);
      u32x4 u;
      u.x = bfpair(f0.x, f0.y); u.y = bfpair(f0.z, f0.w);
      u.z = bfpair(f1.x, f1.y); u.w = bfpair(f1.z, f1.w);
      qfA[c] = __builtin_bit_cast(bf16x8, u);
      f0 = *(const float4*)(qrowB + 32 * c + 8 * qq);
      f1 = *(const float4*)(qrowB + 32 * c + 8 * qq + 4);
      u.x = bfpair(f0.x, f0.y); u.y = bfpair(f0.z, f0.w);
      u.z = bfpair(f1.x, f1.y); u.w = bfpair(f1.z, f1.w);
      qfB[c] = __builtin_bit_cast(bf16x8, u);
    }
  }

  f32x4 oA[8], oB[8];
#pragma unroll
  for (int n = 0; n < 8; ++n) { oA[n] = (f32x4){0,0,0,0}; oB[n] = (f32x4){0,0,0,0}; }
  float denA = 0.f, denB = 0.f;

  const unsigned short* kt = kb + bhS * DHEAD;
  const unsigned short* vt = vtb + (size_t)bh * DHEAD * S_LEN;

  // ---- stage this team's 32-j tile of `pair` into buffer set: 9 vmem ops per wave ----
  auto stage = [&](int pair, int set) {
    const int j0 = pair * 64 + tp * 32;
    const int bi = set * 2 + tp;
#pragma unroll
    for (int a = 0; a < 4; ++a) {
      const int m = iw * 256 + a * 64 + l;      // physical 16B unit (0..511)
      const int u = m ^ ((m >> 4) & 7);         // logical unit (involution)
      gload_lds16(kt + ((size_t)(j0 + (u >> 4))) * DHEAD + (u & 15) * 8,
                  &kbuf[bi][(iw * 256 + a * 64) * 16]);
    }
#pragma unroll
    for (int a = 0; a < 4; ++a) {
      const int m = iw * 256 + a * 64 + l;
      const int u = m ^ ((m >> 3) & 7);
      gload_lds16(vt + (size_t)(u >> 2) * S_LEN + j0 + (u & 3) * 8,
                  &vbuf[bi][(iw * 256 + a * 64) * 16]);
    }
    if (l < 32) gload_lds4(garr + bhS + j0 + l, &g_sh[bi][0]);
  };

  // ---- per-tile compute on buffer bi: both fragments share every LDS read ----
  auto body = [&](int j0, int bi, bool diag) {
    __builtin_amdgcn_s_setprio(1);
    f32x4 sA0 = {0,0,0,0}, sA1 = {0,0,0,0}, sB0 = {0,0,0,0}, sB1 = {0,0,0,0};
#pragma unroll
    for (int c = 0; c < 4; ++c) {
      const int u0 = ((r)      * 16 + 4 * c + qq) ^ (r & 7);
      const int u1 = ((16 + r) * 16 + 4 * c + qq) ^ (r & 7);
      bf16x8 ka0 = *(const bf16x8*)&kbuf[bi][u0 * 16];
      bf16x8 ka1 = *(const bf16x8*)&kbuf[bi][u1 * 16];
      sA0 = __builtin_amdgcn_mfma_f32_16x16x32_bf16(ka0, qfA[c], sA0, 0, 0, 0);
      sB0 = __builtin_amdgcn_mfma_f32_16x16x32_bf16(ka0, qfB[c], sB0, 0, 0, 0);
      sA1 = __builtin_amdgcn_mfma_f32_16x16x32_bf16(ka1, qfA[c], sA1, 0, 0, 0);
      sB1 = __builtin_amdgcn_mfma_f32_16x16x32_bf16(ka1, qfB[c], sB1, 0, 0, 0);
    }
    __builtin_amdgcn_s_setprio(0);

    // gated weights; expA computed, expB = expA * rAB
    unsigned PA0[2], PA1[2], PB0[2], PB1[2];
    {
      float wa[4], wb[4];
#pragma unroll
      for (int m = 0; m < 4; ++m) {
        const int jl = 4 * qq + m;
        const float e = __expf(g_sh[bi][jl] - gmA);
        float a = sA0[m] * e;
        float bq = sB0[m] * e * rAB;
        if (diag) {
          if (j0 + jl > grA) a = 0.f;
          if (j0 + jl > grB) bq = 0.f;
        }
        wa[m] = a; wb[m] = bq; denA += a; denB += bq;
      }
      PA0[0] = cvtpk(wa[0], wa[1]); PA0[1] = cvtpk(wa[2], wa[3]);
      PB0[0] = cvtpk(wb[0], wb[1]); PB0[1] = cvtpk(wb[2], wb[3]);
#pragma unroll
      for (int m = 0; m < 4; ++m) {
        const int jl = 16 + 4 * qq + m;
        const float e = __expf(g_sh[bi][jl] - gmA);
        float a = sA1[m] * e;
        float bq = sB1[m] * e * rAB;
        if (diag) {
          if (j0 + jl > grA) a = 0.f;
          if (j0 + jl > grB) bq = 0.f;
        }
        wa[m] = a; wb[m] = bq; denA += a; denB += bq;
      }
      PA1[0] = cvtpk(wa[0], wa[1]); PA1[1] = cvtpk(wa[2], wa[3]);
      PB1[0] = cvtpk(wb[0], wb[1]); PB1[1] = cvtpk(wb[2], wb[3]);
    }

    // in-register exchange: C-layout -> A-fragment (j = 8qq + 0..7), per fragment
    unsigned AA[4], AB[4];
#pragma unroll
    for (int m = 0; m < 4; ++m) {
      const int srcl = r + 16 * (2 * (qq & 1) + (m >> 1));
      const unsigned a0 = (unsigned)__shfl((int)PA0[m & 1], srcl);
      const unsigned a1 = (unsigned)__shfl((int)PA1[m & 1], srcl);
      const unsigned b0 = (unsigned)__shfl((int)PB0[m & 1], srcl);
      const unsigned b1 = (unsigned)__shfl((int)PB1[m & 1], srcl);
      AA[m] = (qq < 2) ? a0 : a1;
      AB[m] = (qq < 2) ? b0 : b1;
    }
    u32x4 ua, ub;
    ua.x = AA[0]; ua.y = AA[1]; ua.z = AA[2]; ua.w = AA[3];
    ub.x = AB[0]; ub.y = AB[1]; ub.z = AB[2]; ub.w = AB[3];
    const bf16x8 paA = __builtin_bit_cast(bf16x8, ua);
    const bf16x8 paB = __builtin_bit_cast(bf16x8, ub);

    // PV: each V read feeds both fragments
    __builtin_amdgcn_s_setprio(1);
#pragma unroll
    for (int n = 0; n < 8; ++n) {
      const int ud = (16 * n + r) * 4 + qq;
      const int up = ud ^ ((ud >> 3) & 7);
      bf16x8 vb = *(const bf16x8*)&vbuf[bi][up * 16];
      oA[n] = __builtin_amdgcn_mfma_f32_16x16x32_bf16(paA, vb, oA[n], 0, 0, 0);
      oB[n] = __builtin_amdgcn_mfma_f32_16x16x32_bf16(paB, vb, oB[n], 0, 0, 0);
    }
    __builtin_amdgcn_s_setprio(0);
  };

  stage(0, 0);
  for (int p = 0; p < qb; ++p) {
    stage(p + 1, (p + 1) & 1);
    asm volatile("s_waitcnt vmcnt(9)" ::: "memory");  // pair p drained, p+1 in flight
    __builtin_amdgcn_sched_barrier(0);
    __syncthreads();
    body(p * 64 + tp * 32, (p & 1) * 2 + tp, false);
    __syncthreads();
  }
  asm volatile("s_waitcnt vmcnt(0)" ::: "memory");
  __builtin_amdgcn_sched_barrier(0);
  __syncthreads();
  body(qb * 64 + tp * 32, (qb & 1) * 2 + tp, true);

  // ---- split-K merge: team1 -> LDS (bank-spread XOR layout), team0 accumulates ----
  float* osh = (float*)&kbuf[0][0];   // 8192 floats, buffers dead now
  __syncthreads();
  const int xsw = (r & 7) << 2;       // bank-spread XOR (applied identically on read)
  if (tp == 1) {
#pragma unroll
    for (int n = 0; n < 8; ++n) {
      const int i0 = ((((16 * n + r) * 2 + iw) * 2 + 0) * 16 + 4 * qq) ^ xsw;
      const int i1 = ((((16 * n + r) * 2 + iw) * 2 + 1) * 16 + 4 * qq) ^ xsw;
      *(f32x4*)&osh[i0] = oA[n];
      *(f32x4*)&osh[i1] = oB[n];
    }
    den_sh[iw * 2 + 0][l] = denA;
    den_sh[iw * 2 + 1][l] = denB;
  }
  __syncthreads();
  if (tp == 0) {
    denA += den_sh[iw * 2 + 0][l];
    denB += den_sh[iw * 2 + 1][l];
#pragma unroll
    for (int n = 0; n < 8; ++n) {
      const int i0 = ((((16 * n + r) * 2 + iw) * 2 + 0) * 16 + 4 * qq) ^ xsw;
      const int i1 = ((((16 * n + r) * 2 + iw) * 2 + 1) * 16 + 4 * qq) ^ xsw;
      oA[n] += *(const f32x4*)&osh[i0];
      oB[n] += *(const f32x4*)&osh[i1];
    }

    const float* wrow = wgt + h * DHEAD;
    float wv_n[8];
#pragma unroll
    for (int n = 0; n < 8; ++n) wv_n[n] = wrow[16 * n + r];

#pragma unroll
    for (int fg = 0; fg < 2; ++fg) {
      float den_f = (fg == 0) ? denA : denB;
      den_f += __shfl_xor(den_f, 16);
      den_f += __shfl_xor(den_f, 32);
#pragma unroll
      for (int m = 0; m < 4; ++m) {
        const int iloc = 4 * qq + m;
        const float den_o = __shfl(den_f, iloc);
        const int grow = qb * 64 + 4 * iloc + 2 * iw + fg;
        const float csg = cs[bhS + grow];
        const float gmg = gmax[bhS + grow];
        const float norm = fmaxf(fabsf(den_o), __expf(-(csg + gmg))) + EPS_NORM;
        const float inv = 1.f / norm;
        float hv[8];
        float s1 = 0.f, s2 = 0.f;
#pragma unroll
        for (int n = 0; n < 8; ++n) {
          hv[n] = ((fg == 0) ? oA[n][m] : oB[n][m]) * inv;
          s1 += hv[n]; s2 += hv[n] * hv[n];
        }
        s1 += __shfl_xor(s1, 1); s1 += __shfl_xor(s1, 2);
        s1 += __shfl_xor(s1, 4); s1 += __shfl_xor(s1, 8);
        s2 += __shfl_xor(s2, 1); s2 += __shfl_xor(s2, 2);
        s2 += __shfl_xor(s2, 4); s2 += __shfl_xor(s2, 8);
        const float mu  = s1 * (1.f / 128.f);
        const float var = s2 * (1.f / 128.f) - mu * mu;
        const float rstd = rsqrtf(var + LN_EPS_C);
        float* orow = out + ((size_t)b * S_LEN + grow) * E_DIM + h * DHEAD;
#pragma unroll
        for (int n = 0; n < 8; ++n)
          orow[16 * n + r] = (hv[n] - mu) * rstd * wv_n[n];
      }
    }
  }
}

// ---------------- Kernel 3 (fallback, round-2 verified): fp32 staged in-loop ----------------
__global__ __launch_bounds__(256) void mlstm_mfma(
    const float* __restrict__ q, const float* __restrict__ k, const float* __restrict__ v,
    const float* __restrict__ cs, const float* __restrict__ garr, const float* __restrict__ gmax,
    const float* __restrict__ wgt, float* __restrict__ out) {
  __shared__ unsigned short k_lds[32][136];
  __shared__ unsigned int   vt_u32[128][20];
  __shared__ unsigned int   xch[4][16][20];
  __shared__ float          g_sh[32];

  const int bid = blockIdx.x;
  int qt;
  if (bid < 256) qt = 31 - (bid >> 4);
  else           qt = (bid - 256) >> 4;
  const int bh = bid & 15;
  const int b = bh >> 3, h = bh & 7;
  const int t = threadIdx.x;
  const int w = t >> 6;
  const int l = t & 63;
  const int r = l & 15;
  const int qq = l >> 4;
  const size_t bhS = (size_t)bh * S_LEN;

  const int gr = qt * 64 + 4 * r + w;
  const float gm_lane = gmax[bhS + gr];

  bf16x8 qfrag[4];
  {
    const float* qrow = q + ((size_t)b * S_LEN + gr) * E_DIM + h * DHEAD;
#pragma unroll
    for (int c = 0; c < 4; ++c) {
      const float4 f0 = *(const float4*)(qrow + 32 * c + 8 * qq);
      const float4 f1 = *(const float4*)(qrow + 32 * c + 8 * qq + 4);
      u32x4 u;
      u.x = bfpair(f0.x, f0.y); u.y = bfpair(f0.z, f0.w);
      u.z = bfpair(f1.x, f1.y); u.w = bfpair(f1.z, f1.w);
      qfrag[c] = __builtin_bit_cast(bf16x8, u);
    }
  }

  f32x4 o[8];
#pragma unroll
  for (int n = 0; n < 8; ++n) o[n] = (f32x4){0.f, 0.f, 0.f, 0.f};
  float den_p = 0.f;

  const int kj = t >> 3, ks = t & 7;
  const int vjp = t & 15, vds = t >> 4;

  const int ntiles = 2 * qt + 2;
  for (int jt = 0; jt < ntiles; ++jt) {
    const int j0 = jt * 32;
    {
      const float* src = k + ((size_t)b * S_LEN + j0 + kj) * E_DIM + h * DHEAD + ks * 16;
      float4 f0 = *(const float4*)(src);
      float4 f1 = *(const float4*)(src + 4);
      float4 f2 = *(const float4*)(src + 8);
      float4 f3 = *(const float4*)(src + 12);
      u32x4 ua, ub;
      ua.x = bfpair(f0.x, f0.y); ua.y = bfpair(f0.z, f0.w);
      ua.z = bfpair(f1.x, f1.y); ua.w = bfpair(f1.z, f1.w);
      ub.x = bfpair(f2.x, f2.y); ub.y = bfpair(f2.z, f2.w);
      ub.z = bfpair(f3.x, f3.y); ub.w = bfpair(f3.z, f3.w);
      *(u32x4*)&k_lds[kj][ks * 16]     = ua;
      *(u32x4*)&k_lds[kj][ks * 16 + 8] = ub;
    }
    {
      const float* s0 = v + ((size_t)b * S_LEN + j0 + 2 * vjp) * E_DIM + h * DHEAD + vds * 8;
      const float* s1 = s0 + E_DIM;
      float4 a0 = *(const float4*)(s0);
      float4 a1 = *(const float4*)(s0 + 4);
      float4 b0 = *(const float4*)(s1);
      float4 b1 = *(const float4*)(s1 + 4);
      vt_u32[vds * 8 + 0][vjp] = bfpair(a0.x, b0.x);
      vt_u32[vds * 8 + 1][vjp] = bfpair(a0.y, b0.y);
      vt_u32[vds * 8 + 2][vjp] = bfpair(a0.z, b0.z);
      vt_u32[vds * 8 + 3][vjp] = bfpair(a0.w, b0.w);
      vt_u32[vds * 8 + 4][vjp] = bfpair(a1.x, b1.x);
      vt_u32[vds * 8 + 5][vjp] = bfpair(a1.y, b1.y);
      vt_u32[vds * 8 + 6][vjp] = bfpair(a1.z, b1.z);
      vt_u32[vds * 8 + 7][vjp] = bfpair(a1.w, b1.w);
    }
    if (t < 32) g_sh[t] = garr[bhS + j0 + t];
    __syncthreads();

    f32x4 st0 = {0, 0, 0, 0}, st1 = {0, 0, 0, 0};
#pragma unroll
    for (int c = 0; c < 4; ++c) {
      bf16x8 ka0 = *(const bf16x8*)&k_lds[r][32 * c + 8 * qq];
      bf16x8 ka1 = *(const bf16x8*)&k_lds[16 + r][32 * c + 8 * qq];
      st0 = __builtin_amdgcn_mfma_f32_16x16x32_bf16(ka0, qfrag[c], st0, 0, 0, 0);
      st1 = __builtin_amdgcn_mfma_f32_16x16x32_bf16(ka1, qfrag[c], st1, 0, 0, 0);
    }

    const bool diag = (jt >= 2 * qt);
    float wv0[4], wv1[4];
#pragma unroll
    for (int reg = 0; reg < 4; ++reg) {
      const int jl0 = 4 * qq + reg, jl1 = 16 + 4 * qq + reg;
      const float e0 = __expf(g_sh[jl0] - gm_lane);
      const float e1 = __expf(g_sh[jl1] - gm_lane);
      float w0 = st0[reg] * RSQ_DH * e0;
      float w1 = st1[reg] * RSQ_DH * e1;
      if (diag) {
        if (j0 + jl0 > gr) w0 = 0.f;
        if (j0 + jl1 > gr) w1 = 0.f;
      }
      wv0[reg] = w0; wv1[reg] = w1;
      den_p += w0 + w1;
    }

    u32x2 p0, p1;
    p0.x = bfpair(wv0[0], wv0[1]); p0.y = bfpair(wv0[2], wv0[3]);
    p1.x = bfpair(wv1[0], wv1[1]); p1.y = bfpair(wv1[2], wv1[3]);
    *(u32x2*)&xch[w][r][2 * qq]     = p0;
    *(u32x2*)&xch[w][r][8 + 2 * qq] = p1;
    __builtin_amdgcn_wave_barrier();
    bf16x8 pa = *(const bf16x8*)&xch[w][r][4 * qq];
    __builtin_amdgcn_wave_barrier();

#pragma unroll
    for (int n = 0; n < 8; ++n) {
      bf16x8 vb = *(const bf16x8*)&vt_u32[16 * n + r][4 * qq];
      o[n] = __builtin_amdgcn_mfma_f32_16x16x32_bf16(pa, vb, o[n], 0, 0, 0);
    }
    __syncthreads();
  }

  float den_f = den_p;
  den_f += __shfl_xor(den_f, 16);
  den_f += __shfl_xor(den_f, 32);

  const float* wrow = wgt + h * DHEAD;
  float wv_n[8];
#pragma unroll
  for (int n = 0; n < 8; ++n) wv_n[n] = wrow[16 * n + r];

#pragma unroll
  for (int reg = 0; reg < 4; ++reg) {
    const int iloc = 4 * qq + reg;
    const float den_o = __shfl(den_f, iloc);
    const int grow = qt * 64 + 4 * iloc + w;
    const float csg = cs[bhS + grow];
    const float gmg = gmax[bhS + grow];
    const float norm = fmaxf(fabsf(den_o), __expf(-(csg + gmg))) + EPS_NORM;
    const float inv = 1.f / norm;
    float hv[8];
    float s1 = 0.f, s2 = 0.f;
#pragma unroll
    for (int n = 0; n < 8; ++n) {
      hv[n] = o[n][reg] * inv;
      s1 += hv[n]; s2 += hv[n] * hv[n];
    }
    s1 += __shfl_xor(s1, 1); s1 += __shfl_xor(s1, 2);
    s1 += __shfl_xor(s1, 4); s1 += __shfl_xor(s1, 8);
    s2 += __shfl_xor(s2, 1); s2 += __shfl_xor(s2, 2);
    s2 += __shfl_xor(s2, 4); s2 += __shfl_xor(s2, 8);
    const float mu  = s1 * (1.f / 128.f);
    const float var = s2 * (1.f / 128.f) - mu * mu;
    const float rstd = rsqrtf(var + LN_EPS_C);
    float* orow = out + ((size_t)b * S_LEN + grow) * E_DIM + h * DHEAD;
#pragma unroll
    for (int n = 0; n < 8; ++n)
      orow[16 * n + r] = (hv[n] - mu) * rstd * wv_n[n];
  }
}

extern "C" void kernel_launch(void* const* d_in, const int* in_sizes, int n_in,
                              void* d_out, int out_size, void* d_ws, size_t ws_size,
                              hipStream_t stream) {
  (void)in_sizes; (void)n_in; (void)out_size;
  const float* q   = (const float*)d_in[0];
  const float* k   = (const float*)d_in[1];
  const float* v   = (const float*)d_in[2];
  const float* Wi  = (const float*)d_in[3];
  const float* bi  = (const float*)d_in[4];
  const float* Wf  = (const float*)d_in[5];
  const float* bf  = (const float*)d_in[6];
  const float* wgt = (const float*)d_in[7];
  float* out = (float*)d_out;
  float* ws  = (float*)d_ws;
  const int BNS = 2 * NHEAD * S_LEN;              // 32768
  float* ig_pre = ws;
  float* fg_pre = ws + (size_t)BNS;
  float* cs     = ws + (size_t)2 * BNS;
  float* gv     = ws + (size_t)3 * BNS;
  float* gmaxs  = ws + (size_t)4 * BNS;
  unsigned short* kb  = (unsigned short*)(ws + (size_t)5 * BNS);
  unsigned short* vtb = kb + (size_t)16 * S_LEN * DHEAD;

  const size_t need = (size_t)5 * BNS * 4 + (size_t)2 * 16 * S_LEN * DHEAD * 2;

  if (ws_size >= need) {
    gates_fused<<<1024, 256, 0, stream>>>(q, k, v, Wi, bi, Wf, bf, ig_pre, fg_pre, kb);
    vtrans<<<512, 256, 0, stream>>>(v, vtb);
    scan_kernel<<<16, 256, 0, stream>>>(ig_pre, fg_pre, cs, gv, gmaxs, LNRSQ);
    mlstm_mfma9<<<512, 256, 0, stream>>>(kb, vtb, q, cs, gv, gmaxs, wgt, out);
  } else {
    gates_fused<<<1024, 256, 0, stream>>>(q, k, v, Wi, bi, Wf, bf, ig_pre, fg_pre, nullptr);
    scan_kernel<<<16, 256, 0, stream>>>(ig_pre, fg_pre, cs, gv, gmaxs, 0.0f);
    mlstm_mfma<<<512, 256, 0, stream>>>(q, k, v, cs, gv, gmaxs, wgt, out);
  }
}